// Round 1
// baseline (1867.362 us; speedup 1.0000x reference)
//
#include <hip/hip_runtime.h>
#include <math.h>

#define N     8192
#define BS    2
#define KNN   16
#define SUP   7
#define KC    128
#define SK    (SUP*KC)   // 896
#define CAP   128
#define NCH   8
#define CH    (N/NCH)    // 1024
#define QG    256
#define PPB   64
#define OPB   8

__device__ __forceinline__ float dist2(float4 a, float4 b) {
    float dx = a.x - b.x, dy = a.y - b.y, dz = a.z - b.z;
    return fmaf(dx, dx, fmaf(dy, dy, dz * dz));
}

// ---------------------------------------------------------------- prep
__global__ void k_prep(const float* __restrict__ verts, const float* __restrict__ dirs,
                       const float* __restrict__ wste, const float* __restrict__ wconv,
                       float4* __restrict__ vb4, float4* __restrict__ sup4,
                       float4* __restrict__ wste4, float4* __restrict__ wt4) {
    int t = blockIdx.x * blockDim.x + threadIdx.x;
    if (t < BS * N)
        vb4[t] = make_float4(verts[t*3], verts[t*3+1], verts[t*3+2], 0.f);
    int u = t - BS * N;
    if (u >= 0 && u < SK) {
        float x = dirs[u], y = dirs[SK + u], z = dirs[2*SK + u];
        float inv = 1.f / fmaxf(sqrtf(fmaf(x, x, fmaf(y, y, z*z))), 1e-12f);
        sup4[u] = make_float4(x*inv, y*inv, z*inv, 0.f);
    }
    int v = u - SK;
    if (v >= 0 && v < KC)
        wste4[v] = make_float4(wste[v*3], wste[v*3+1], wste[v*3+2], 0.f);
    int w = v - KC;
    if (w >= 0 && w < 32*KC) {
        int c4 = w >> 7, k = w & 127;
        const float* r = wconv + k*2*KC + c4*4;   // W1 half, transposed to [c4][k]
        wt4[w] = make_float4(r[0], r[1], r[2], r[3]);
    }
}

// ------------------------------------------------- per-query radius from sample
__global__ void k_thr(const float4* __restrict__ vb4, float* __restrict__ thr) {
    int b = blockIdx.y;
    int i = blockIdx.x * 256 + threadIdx.x;
    const float4* vb = vb4 + b * N;
    float4 q = vb[i];
    float b0 = 3.4e38f, b1 = 3.4e38f, b2 = 3.4e38f, b3 = 3.4e38f;
    for (int s = 0; s < N/16; ++s) {
        int j = s * 16;                          // uniform sample -> scalar/broadcast load
        float d = dist2(q, vb[j]);
        if (j == i) d = 3.4e38f;
        float t0 = fminf(b0, d); float r = fmaxf(b0, d); b0 = t0;
        float t1 = fminf(b1, r); r = fmaxf(b1, r); b1 = t1;
        float t2 = fminf(b2, r); r = fmaxf(b2, r); b2 = t2;
        b3 = fminf(b3, r);
    }
    thr[b*N + i] = b3;                           // 4th-smallest sampled distance
}

// ------------------------------------------------- filtered candidate append
__global__ void k_append(const float4* __restrict__ vb4, const float* __restrict__ thr,
                         int* __restrict__ cnt, int* __restrict__ cand) {
    __shared__ float4 pts[CH];
    int b = blockIdx.z, qg = blockIdx.x, c = blockIdx.y;
    const float4* vb = vb4 + b * N;
    int base = c * CH;
    for (int t = threadIdx.x; t < CH; t += 256) pts[t] = vb[base + t];
    __syncthreads();
    int i = qg * QG + threadIdx.x;
    float4 q = vb[i];
    float t0 = thr[b*N + i];
    int* mycand = cand + (size_t)(b*N + i) * CAP;
    int* mycnt  = cnt + b*N + i;
    for (int j = 0; j < CH; ++j) {
        float d = dist2(q, pts[j]);              // broadcast LDS read
        int gj = base + j;
        if (d <= t0 && gj != i) {
            int p = atomicAdd(mycnt, 1);
            if (p < CAP) mycand[p] = gj;
        }
    }
}

// ------------------------------------------------- exact top-16 from candidates
__global__ void k_select(const float4* __restrict__ vb4, const int* __restrict__ cnt,
                         const int* __restrict__ cand, int* __restrict__ idxout) {
    int b = blockIdx.y;
    int i = blockIdx.x * 256 + threadIdx.x;
    const float4* vb = vb4 + b * N;
    float4 q = vb[i];
    int n = cnt[b*N + i];
    const int* mycand = cand + (size_t)(b*N + i) * CAP;
    unsigned long long key[KNN];
#pragma unroll
    for (int t = 0; t < KNN; ++t) key[t] = ~0ull;
    if (n >= KNN && n <= CAP) {
        for (int p = 0; p < n; ++p) {
            int j = mycand[p];
            float d = dist2(q, vb[j]);
            unsigned long long k = ((unsigned long long)__float_as_uint(d) << 32) | (unsigned)j;
            if (k < key[KNN-1]) {
#pragma unroll
                for (int t = 0; t < KNN; ++t) {
                    unsigned long long lo = key[t] < k ? key[t] : k;
                    unsigned long long hi = key[t] < k ? k : key[t];
                    key[t] = lo; k = hi;
                }
            }
        }
    } else {
        // exact fallback (thr mis-estimate; ~never on random data)
        for (int j = 0; j < N; ++j) {
            if (j == i) continue;
            float d = dist2(q, vb[j]);
            unsigned long long k = ((unsigned long long)__float_as_uint(d) << 32) | (unsigned)j;
            if (k < key[KNN-1]) {
#pragma unroll
                for (int t = 0; t < KNN; ++t) {
                    unsigned long long lo = key[t] < k ? key[t] : k;
                    unsigned long long hi = key[t] < k ? k : key[t];
                    key[t] = lo; k = hi;
                }
            }
        }
    }
    int* oi = idxout + (size_t)(b*N + i) * KNN;
#pragma unroll
    for (int t = 0; t < KNN; ++t) oi[t] = (int)(key[t] & 0xffffffffu);
}

// ------------------------------------------------- graph conv feature (n,128)
__global__ void k_feature(const float4* __restrict__ vb4, const float4* __restrict__ sup4,
                          const int* __restrict__ idx, float* __restrict__ feat) {
    int b = blockIdx.y, i = blockIdx.x;
    __shared__ float4 dirn[KNN];
    const float4* vb = vb4 + b * N;
    if (threadIdx.x < KNN) {
        int j = idx[(size_t)(b*N + i)*KNN + threadIdx.x];
        float4 q = vb[i], p = vb[j];
        float dx = p.x - q.x, dy = p.y - q.y, dz = p.z - q.z;
        float inv = 1.f / fmaxf(sqrtf(fmaf(dx, dx, fmaf(dy, dy, dz*dz))), 1e-12f);
        dirn[threadIdx.x] = make_float4(dx*inv, dy*inv, dz*inv, 0.f);
    }
    __syncthreads();
    int k = threadIdx.x;
    float acc = 0.f;
#pragma unroll
    for (int s = 0; s < SUP; ++s) {
        float4 sv = sup4[s*KC + k];
        float m = 0.f;                            // relu folded into max (all maxes >= 0)
#pragma unroll
        for (int K = 0; K < KNN; ++K) {
            float4 dn = dirn[K];
            float t = fmaf(dn.x, sv.x, fmaf(dn.y, sv.y, dn.z*sv.z));
            m = fmaxf(m, t);
        }
        acc += m;
    }
    feat[(size_t)(b*N + i)*KC + k] = acc * (1.f/SUP);
}

// ------------------------------------------------- neighbor-max + partial mean
__global__ void k_nbmax(const float* __restrict__ feat, const int* __restrict__ idx,
                        float* __restrict__ partial) {
    int b = blockIdx.y;
    int p0 = blockIdx.x * PPB;
    int k = threadIdx.x;
    const float* fb = feat + (size_t)b*N*KC;
    float sum = 0.f;
    for (int p = 0; p < PPB; ++p) {
        const int* ii = idx + (size_t)(b*N + p0 + p) * KNN;
        float m = -3.4e38f;
#pragma unroll
        for (int K = 0; K < KNN; ++K)
            m = fmaxf(m, fb[(size_t)ii[K]*KC + k]);
        sum += m;
    }
    partial[(size_t)(b*(N/PPB) + blockIdx.x)*KC + k] = sum;
}

// ------------------------------------------------- global vec + W2 fold
__global__ void k_global(const float* __restrict__ partial, const float* __restrict__ wconv,
                         float* __restrict__ gconst) {
    int b = blockIdx.x, k = threadIdx.x;
    float s = 0.f;
    for (int q = 0; q < N/PPB; ++q) s += partial[(size_t)(b*(N/PPB) + q)*KC + k];
    __shared__ float fg[KC];
    fg[k] = s * (1.f/N);
    __syncthreads();
    float acc = 0.f;
    for (int c = 0; c < KC; ++c)
        acc = fmaf(fg[c], wconv[k*2*KC + KC + c], acc);
    gconst[b*KC + k] = acc;
}

// ------------------------------------------------- epilogue GEMM + STE + add
__global__ void k_out(const float* __restrict__ feat, const float4* __restrict__ wt4,
                      const float4* __restrict__ wste4, const float4* __restrict__ vb4,
                      const float* __restrict__ gconst, float* __restrict__ out) {
    int p0 = blockIdx.x * OPB;
    int k = threadIdx.x;
    float acc[OPB];
#pragma unroll
    for (int p = 0; p < OPB; ++p) acc[p] = 0.f;
#pragma unroll 4
    for (int c4 = 0; c4 < KC/4; ++c4) {
        float4 w = wt4[c4*KC + k];
#pragma unroll
        for (int p = 0; p < OPB; ++p) {
            const float4 f = *(const float4*)(feat + (size_t)(p0 + p)*KC + c4*4);
            acc[p] = fmaf(f.x, w.x, fmaf(f.y, w.y, fmaf(f.z, w.z, fmaf(f.w, w.w, acc[p]))));
        }
    }
    float4 ws = wste4[k];
#pragma unroll
    for (int p = 0; p < OPB; ++p) {
        int pt = p0 + p;
        int b = pt >> 13;                        // / N
        float4 v = vb4[pt];
        float fste = fmaf(v.x, ws.x, fmaf(v.y, ws.y, v.z*ws.z));
        out[(size_t)pt*KC + k] = acc[p] + gconst[b*KC + k] + feat[(size_t)pt*KC + k] + fste;
    }
}

extern "C" void kernel_launch(void* const* d_in, const int* in_sizes, int n_in,
                              void* d_out, int out_size, void* d_ws, size_t ws_size,
                              hipStream_t stream) {
    const float* verts = (const float*)d_in[0];
    const float* dirs  = (const float*)d_in[1];
    const float* wste  = (const float*)d_in[2];
    const float* wconv = (const float*)d_in[3];
    float* out = (float*)d_out;

    // workspace layout (floats); cand (8MB) is dead after k_select and aliased as feat
    float* ws = (float*)d_ws;
    float4* vb4   = (float4*)ws;                  // BS*N          (65536 f)
    float4* sup4  = vb4 + BS*N;                   // SK            (3584 f)
    float4* wste4 = sup4 + SK;                    // KC            (512 f)
    float4* wt4   = wste4 + KC;                   // 32*KC         (16384 f)
    float*  thr   = (float*)(wt4 + 32*KC);        // BS*N
    int*    cnt   = (int*)(thr + BS*N);           // BS*N
    int*    cand  = cnt + BS*N;                   // BS*N*CAP
    float*  feat  = (float*)cand;                 // BS*N*KC  (alias: same size)
    int*    idx   = cand + (size_t)BS*N*CAP;      // BS*N*KNN
    float*  partial = (float*)(idx + (size_t)BS*N*KNN);  // BS*(N/PPB)*KC
    float*  gconst  = partial + (size_t)BS*(N/PPB)*KC;   // BS*KC

    hipMemsetAsync(cnt, 0, (size_t)BS*N*sizeof(int), stream);
    k_prep<<<(BS*N + SK + KC + 32*KC + 255)/256, 256, 0, stream>>>(verts, dirs, wste, wconv,
                                                                   vb4, sup4, wste4, wt4);
    k_thr<<<dim3(N/256, BS), 256, 0, stream>>>(vb4, thr);
    k_append<<<dim3(N/QG, NCH, BS), 256, 0, stream>>>(vb4, thr, cnt, cand);
    k_select<<<dim3(N/256, BS), 256, 0, stream>>>(vb4, cnt, cand, idx);
    k_feature<<<dim3(N, BS), KC, 0, stream>>>(vb4, sup4, idx, feat);
    k_nbmax<<<dim3(N/PPB, BS), KC, 0, stream>>>(feat, idx, partial);
    k_global<<<BS, KC, 0, stream>>>(partial, wconv, gconst);
    k_out<<<BS*N/OPB, KC, 0, stream>>>(feat, wt4, wste4, vb4, gconst, out);
}

// Round 2
// 617.512 us; speedup vs baseline: 3.0240x; 3.0240x over previous
//
#include <hip/hip_runtime.h>
#include <math.h>

#define N     8192
#define BS    2
#define KNN   16
#define SUP   7
#define KC    128
#define SK    (SUP*KC)   // 896
#define CAP   128
#define NCH   8
#define CH    (N/NCH)    // 1024
#define QG    256
#define PPB   64
#define OPB   8

typedef unsigned long long ull;

__device__ __forceinline__ float dist2(float4 a, float4 b) {
    float dx = a.x - b.x, dy = a.y - b.y, dz = a.z - b.z;
    return fmaf(dx, dx, fmaf(dy, dy, dz * dz));
}

// sorted-insert chain over 16 NAMED u64 registers (guaranteed no scratch)
#define SW(Kt) { ull _lo = (Kt < _n) ? Kt : _n; ull _hi = (Kt < _n) ? _n : Kt; Kt = _lo; _n = _hi; }
#define INS16(NK) do { ull _n = (NK); if (_n < K15) { \
    SW(K0) SW(K1) SW(K2) SW(K3) SW(K4) SW(K5) SW(K6) SW(K7) \
    SW(K8) SW(K9) SW(K10) SW(K11) SW(K12) SW(K13) SW(K14) SW(K15) } } while(0)

#define DECL16 ull K0=~0ull,K1=~0ull,K2=~0ull,K3=~0ull,K4=~0ull,K5=~0ull,K6=~0ull,K7=~0ull, \
                   K8=~0ull,K9=~0ull,K10=~0ull,K11=~0ull,K12=~0ull,K13=~0ull,K14=~0ull,K15=~0ull;

// ---------------------------------------------------------------- prep
__global__ void k_prep(const float* __restrict__ verts, const float* __restrict__ dirs,
                       const float* __restrict__ wste, const float* __restrict__ wconv,
                       float4* __restrict__ vb4, float4* __restrict__ sup4,
                       float4* __restrict__ wste4, float4* __restrict__ wt4) {
    int t = blockIdx.x * blockDim.x + threadIdx.x;
    if (t < BS * N)
        vb4[t] = make_float4(verts[t*3], verts[t*3+1], verts[t*3+2], 0.f);
    int u = t - BS * N;
    if (u >= 0 && u < SK) {
        float x = dirs[u], y = dirs[SK + u], z = dirs[2*SK + u];
        float inv = 1.f / fmaxf(sqrtf(fmaf(x, x, fmaf(y, y, z*z))), 1e-12f);
        sup4[u] = make_float4(x*inv, y*inv, z*inv, 0.f);
    }
    int v = u - SK;
    if (v >= 0 && v < KC)
        wste4[v] = make_float4(wste[v*3], wste[v*3+1], wste[v*3+2], 0.f);
    int w = v - KC;
    if (w >= 0 && w < 32*KC) {
        int c4 = w >> 7, k = w & 127;
        const float* r = wconv + k*2*KC + c4*4;   // W1 half, transposed to [c4][k]
        wt4[w] = make_float4(r[0], r[1], r[2], r[3]);
    }
}

// ------------------------------------------------- per-query radius from sample
__global__ void k_thr(const float4* __restrict__ vb4, float* __restrict__ thr) {
    int b = blockIdx.y;
    int i = blockIdx.x * 256 + threadIdx.x;
    const float4* vb = vb4 + b * N;
    float4 q = vb[i];
    float b0 = 3.4e38f, b1 = 3.4e38f, b2 = 3.4e38f, b3 = 3.4e38f;
    for (int s = 0; s < N/16; ++s) {
        int j = s * 16;                          // uniform sample -> broadcast load
        float d = dist2(q, vb[j]);
        if (j == i) d = 3.4e38f;
        float t0 = fminf(b0, d); float r = fmaxf(b0, d); b0 = t0;
        float t1 = fminf(b1, r); r = fmaxf(b1, r); b1 = t1;
        float t2 = fminf(b2, r); r = fmaxf(b2, r); b2 = t2;
        b3 = fminf(b3, r);
    }
    thr[b*N + i] = b3;                           // 4th-smallest sampled distance
}

// ------------------------------------------------- filtered candidate append
__global__ void k_append(const float4* __restrict__ vb4, const float* __restrict__ thr,
                         int* __restrict__ cnt, int* __restrict__ cand) {
    __shared__ float4 pts[CH];
    int b = blockIdx.z, qg = blockIdx.x, c = blockIdx.y;
    const float4* vb = vb4 + b * N;
    int base = c * CH;
    for (int t = threadIdx.x; t < CH; t += 256) pts[t] = vb[base + t];
    __syncthreads();
    int i = qg * QG + threadIdx.x;
    float4 q = vb[i];
    float t0 = thr[b*N + i];
    int* mycand = cand + (size_t)(b*N + i) * CAP;
    int* mycnt  = cnt + b*N + i;
    for (int j = 0; j < CH; ++j) {
        float d = dist2(q, pts[j]);              // broadcast LDS read
        int gj = base + j;
        if (d <= t0 && gj != i) {
            int p = atomicAdd(mycnt, 1);
            if (p < CAP) mycand[p] = gj;
        }
    }
}

// ------------------------------------------------- exact top-16 from candidates
__global__ void k_select(const float4* __restrict__ vb4, const int* __restrict__ cnt,
                         const int* __restrict__ cand, int* __restrict__ idxout,
                         int* __restrict__ fbcnt, int* __restrict__ fblist) {
    int b = blockIdx.y;
    int i = blockIdx.x * 256 + threadIdx.x;
    int qi = b*N + i;
    int n = cnt[qi];
    if (n < KNN || n > CAP) {                    // rare: defer to wave-per-query kernel
        int p = atomicAdd(fbcnt, 1);
        fblist[p] = qi;
        return;
    }
    const float4* vb = vb4 + b * N;
    float4 q = vb[i];
    const int* mycand = cand + (size_t)qi * CAP;
    DECL16;
    int jn = mycand[0];
    float4 vn = vb[jn];
    for (int p = 0; p < n; ++p) {
        int j = jn; float4 v = vn;
        if (p + 1 < n) { jn = mycand[p+1]; vn = vb[jn]; }   // prefetch under the chain
        float d = dist2(q, v);
        ull nk = ((ull)__float_as_uint(d) << 32) | (unsigned)j;
        INS16(nk);
    }
    int* oi = idxout + (size_t)qi * KNN;
    oi[0]=(int)(K0&0xffffffffu);  oi[1]=(int)(K1&0xffffffffu);
    oi[2]=(int)(K2&0xffffffffu);  oi[3]=(int)(K3&0xffffffffu);
    oi[4]=(int)(K4&0xffffffffu);  oi[5]=(int)(K5&0xffffffffu);
    oi[6]=(int)(K6&0xffffffffu);  oi[7]=(int)(K7&0xffffffffu);
    oi[8]=(int)(K8&0xffffffffu);  oi[9]=(int)(K9&0xffffffffu);
    oi[10]=(int)(K10&0xffffffffu); oi[11]=(int)(K11&0xffffffffu);
    oi[12]=(int)(K12&0xffffffffu); oi[13]=(int)(K13&0xffffffffu);
    oi[14]=(int)(K14&0xffffffffu); oi[15]=(int)(K15&0xffffffffu);
}

// ------------------------------------------------- exact wave-per-query fallback
__global__ void k_fallback(const float4* __restrict__ vb4, const int* __restrict__ fbcnt,
                           const int* __restrict__ fblist, int* __restrict__ idxout) {
    __shared__ ull heap[64*16];
    int nfb = *fbcnt;
    int lane = threadIdx.x;
    for (int w = blockIdx.x; w < nfb; w += gridDim.x) {
        int qi = fblist[w];
        int b = qi >> 13, i = qi & (N-1);
        const float4* vb = vb4 + b * N;
        float4 q = vb[i];
        DECL16;
        for (int j = lane; j < N; j += 64) {
            if (j == i) continue;
            float d = dist2(q, vb[j]);
            ull nk = ((ull)__float_as_uint(d) << 32) | (unsigned)j;
            INS16(nk);
        }
        heap[lane*16+0]=K0;   heap[lane*16+1]=K1;   heap[lane*16+2]=K2;   heap[lane*16+3]=K3;
        heap[lane*16+4]=K4;   heap[lane*16+5]=K5;   heap[lane*16+6]=K6;   heap[lane*16+7]=K7;
        heap[lane*16+8]=K8;   heap[lane*16+9]=K9;   heap[lane*16+10]=K10; heap[lane*16+11]=K11;
        heap[lane*16+12]=K12; heap[lane*16+13]=K13; heap[lane*16+14]=K14; heap[lane*16+15]=K15;
        __syncthreads();
        int ptr = 0;
        int* oi = idxout + (size_t)qi * KNN;
        for (int r = 0; r < KNN; ++r) {          // 16-round tournament merge
            ull h = (ptr < 16) ? heap[lane*16 + ptr] : ~0ull;
            ull m = h;
#pragma unroll
            for (int s = 1; s < 64; s <<= 1) {
                ull o = __shfl_xor(m, s, 64);
                m = (o < m) ? o : m;
            }
            if (h == m && m != ~0ull) ptr++;
            if (lane == r) oi[r] = (int)(m & 0xffffffffu);
        }
        __syncthreads();
    }
}

// ------------------------------------------------- graph conv feature (n,128)
__global__ void k_feature(const float4* __restrict__ vb4, const float4* __restrict__ sup4,
                          const int* __restrict__ idx, float* __restrict__ feat) {
    int b = blockIdx.y, i = blockIdx.x;
    __shared__ float4 dirn[KNN];
    const float4* vb = vb4 + b * N;
    if (threadIdx.x < KNN) {
        int j = idx[(size_t)(b*N + i)*KNN + threadIdx.x];
        float4 q = vb[i], p = vb[j];
        float dx = p.x - q.x, dy = p.y - q.y, dz = p.z - q.z;
        float inv = 1.f / fmaxf(sqrtf(fmaf(dx, dx, fmaf(dy, dy, dz*dz))), 1e-12f);
        dirn[threadIdx.x] = make_float4(dx*inv, dy*inv, dz*inv, 0.f);
    }
    __syncthreads();
    int k = threadIdx.x;
    float acc = 0.f;
#pragma unroll
    for (int s = 0; s < SUP; ++s) {
        float4 sv = sup4[s*KC + k];
        float m = 0.f;                            // relu folded into max
#pragma unroll
        for (int K = 0; K < KNN; ++K) {
            float4 dn = dirn[K];
            float t = fmaf(dn.x, sv.x, fmaf(dn.y, sv.y, dn.z*sv.z));
            m = fmaxf(m, t);
        }
        acc += m;
    }
    feat[(size_t)(b*N + i)*KC + k] = acc * (1.f/SUP);
}

// ------------------------------------------------- neighbor-max + partial mean
__global__ void k_nbmax(const float* __restrict__ feat, const int* __restrict__ idx,
                        float* __restrict__ partial) {
    int b = blockIdx.y;
    int p0 = blockIdx.x * PPB;
    int k = threadIdx.x;
    const float* fb = feat + (size_t)b*N*KC;
    float sum = 0.f;
    for (int p = 0; p < PPB; ++p) {
        const int* ii = idx + (size_t)(b*N + p0 + p) * KNN;
        float m = -3.4e38f;
#pragma unroll
        for (int K = 0; K < KNN; ++K)
            m = fmaxf(m, fb[(size_t)ii[K]*KC + k]);
        sum += m;
    }
    partial[(size_t)(b*(N/PPB) + blockIdx.x)*KC + k] = sum;
}

// ------------------------------------------------- global vec + W2 fold
__global__ void k_global(const float* __restrict__ partial, const float* __restrict__ wconv,
                         float* __restrict__ gconst) {
    int b = blockIdx.x, k = threadIdx.x;
    float s = 0.f;
    for (int q = 0; q < N/PPB; ++q) s += partial[(size_t)(b*(N/PPB) + q)*KC + k];
    __shared__ float fg[KC];
    fg[k] = s * (1.f/N);
    __syncthreads();
    float acc = 0.f;
    for (int c = 0; c < KC; ++c)
        acc = fmaf(fg[c], wconv[k*2*KC + KC + c], acc);
    gconst[b*KC + k] = acc;
}

// ------------------------------------------------- epilogue GEMM + STE + add
__global__ void k_out(const float* __restrict__ feat, const float4* __restrict__ wt4,
                      const float4* __restrict__ wste4, const float4* __restrict__ vb4,
                      const float* __restrict__ gconst, float* __restrict__ out) {
    int p0 = blockIdx.x * OPB;
    int k = threadIdx.x;
    float acc[OPB];
#pragma unroll
    for (int p = 0; p < OPB; ++p) acc[p] = 0.f;
#pragma unroll 4
    for (int c4 = 0; c4 < KC/4; ++c4) {
        float4 w = wt4[c4*KC + k];
#pragma unroll
        for (int p = 0; p < OPB; ++p) {
            const float4 f = *(const float4*)(feat + (size_t)(p0 + p)*KC + c4*4);
            acc[p] = fmaf(f.x, w.x, fmaf(f.y, w.y, fmaf(f.z, w.z, fmaf(f.w, w.w, acc[p]))));
        }
    }
    float4 ws = wste4[k];
#pragma unroll
    for (int p = 0; p < OPB; ++p) {
        int pt = p0 + p;
        int b = pt >> 13;                        // / N
        float4 v = vb4[pt];
        float fste = fmaf(v.x, ws.x, fmaf(v.y, ws.y, v.z*ws.z));
        out[(size_t)pt*KC + k] = acc[p] + gconst[b*KC + k] + feat[(size_t)pt*KC + k] + fste;
    }
}

extern "C" void kernel_launch(void* const* d_in, const int* in_sizes, int n_in,
                              void* d_out, int out_size, void* d_ws, size_t ws_size,
                              hipStream_t stream) {
    const float* verts = (const float*)d_in[0];
    const float* dirs  = (const float*)d_in[1];
    const float* wste  = (const float*)d_in[2];
    const float* wconv = (const float*)d_in[3];
    float* out = (float*)d_out;

    // workspace layout (floats); cand is dead after select/fallback and aliased as feat
    float* ws = (float*)d_ws;
    float4* vb4   = (float4*)ws;                  // BS*N
    float4* sup4  = vb4 + BS*N;                   // SK
    float4* wste4 = sup4 + SK;                    // KC
    float4* wt4   = wste4 + KC;                   // 32*KC
    float*  thr   = (float*)(wt4 + 32*KC);        // BS*N
    int*    cnt   = (int*)(thr + BS*N);           // BS*N
    int*    fbcnt = cnt + BS*N;                   // 16 (use [0])
    int*    fblist= fbcnt + 16;                   // BS*N
    int*    cand  = fblist + BS*N;                // BS*N*CAP
    float*  feat  = (float*)cand;                 // BS*N*KC  (alias: same size)
    int*    idx   = cand + (size_t)BS*N*CAP;      // BS*N*KNN
    float*  partial = (float*)(idx + (size_t)BS*N*KNN);  // BS*(N/PPB)*KC
    float*  gconst  = partial + (size_t)BS*(N/PPB)*KC;   // BS*KC

    hipMemsetAsync(cnt, 0, (size_t)(BS*N + 16)*sizeof(int), stream);  // cnt + fbcnt
    k_prep<<<(BS*N + SK + KC + 32*KC + 255)/256, 256, 0, stream>>>(verts, dirs, wste, wconv,
                                                                   vb4, sup4, wste4, wt4);
    k_thr<<<dim3(N/256, BS), 256, 0, stream>>>(vb4, thr);
    k_append<<<dim3(N/QG, NCH, BS), 256, 0, stream>>>(vb4, thr, cnt, cand);
    k_select<<<dim3(N/256, BS), 256, 0, stream>>>(vb4, cnt, cand, idx, fbcnt, fblist);
    k_fallback<<<2048, 64, 0, stream>>>(vb4, fbcnt, fblist, idx);
    k_feature<<<dim3(N, BS), KC, 0, stream>>>(vb4, sup4, idx, feat);
    k_nbmax<<<dim3(N/PPB, BS), KC, 0, stream>>>(feat, idx, partial);
    k_global<<<BS, KC, 0, stream>>>(partial, wconv, gconst);
    k_out<<<BS*N/OPB, KC, 0, stream>>>(feat, wt4, wste4, vb4, gconst, out);
}

// Round 3
// 497.529 us; speedup vs baseline: 3.7533x; 1.2412x over previous
//
#include <hip/hip_runtime.h>
#include <math.h>

#define N     8192
#define BS    2
#define KNN   16
#define SUP   7
#define KC    128
#define SK    (SUP*KC)   // 896
#define NCH   8
#define CH    (N/NCH)    // 1024
#define SLOTS 16
#define CAP   (NCH*SLOTS) // 128
#define QG    256
#define PPB   64
#define OPB   8

typedef unsigned long long ull;

__device__ __forceinline__ float dist2(float4 a, float4 b) {
    float dx = a.x - b.x, dy = a.y - b.y, dz = a.z - b.z;
    return fmaf(dx, dx, fmaf(dy, dy, dz * dz));
}

// sorted-insert chain over 16 NAMED u64 registers (guaranteed no scratch)
#define SW(Kt) { ull _lo = (Kt < _n) ? Kt : _n; ull _hi = (Kt < _n) ? _n : Kt; Kt = _lo; _n = _hi; }
#define INS16(NK) do { ull _n = (NK); if (_n < K15) { \
    SW(K0) SW(K1) SW(K2) SW(K3) SW(K4) SW(K5) SW(K6) SW(K7) \
    SW(K8) SW(K9) SW(K10) SW(K11) SW(K12) SW(K13) SW(K14) SW(K15) } } while(0)

#define DECL16 ull K0=~0ull,K1=~0ull,K2=~0ull,K3=~0ull,K4=~0ull,K5=~0ull,K6=~0ull,K7=~0ull, \
                   K8=~0ull,K9=~0ull,K10=~0ull,K11=~0ull,K12=~0ull,K13=~0ull,K14=~0ull,K15=~0ull;

// ---------------------------------------------------------------- prep
__global__ void k_prep(const float* __restrict__ verts, const float* __restrict__ dirs,
                       const float* __restrict__ wste, const float* __restrict__ wconv,
                       float4* __restrict__ vb4, float4* __restrict__ sup4,
                       float4* __restrict__ wste4, float4* __restrict__ wt4) {
    int t = blockIdx.x * blockDim.x + threadIdx.x;
    if (t < BS * N)
        vb4[t] = make_float4(verts[t*3], verts[t*3+1], verts[t*3+2], 0.f);
    int u = t - BS * N;
    if (u >= 0 && u < SK) {
        float x = dirs[u], y = dirs[SK + u], z = dirs[2*SK + u];
        float inv = 1.f / fmaxf(sqrtf(fmaf(x, x, fmaf(y, y, z*z))), 1e-12f);
        sup4[u] = make_float4(x*inv, y*inv, z*inv, 0.f);
    }
    int v = u - SK;
    if (v >= 0 && v < KC)
        wste4[v] = make_float4(wste[v*3], wste[v*3+1], wste[v*3+2], 0.f);
    int w = v - KC;
    if (w >= 0 && w < 32*KC) {
        int c4 = w >> 7, k = w & 127;
        const float* r = wconv + k*2*KC + c4*4;   // W1 half, transposed to [c4][k]
        wt4[w] = make_float4(r[0], r[1], r[2], r[3]);
    }
}

// ------------------------------------------------- per-query radius from sample
__global__ void k_thr(const float4* __restrict__ vb4, float* __restrict__ thr) {
    int b = blockIdx.y;
    int i = blockIdx.x * 256 + threadIdx.x;
    const float4* vb = vb4 + b * N;
    float4 q = vb[i];
    float b0 = 3.4e38f, b1 = 3.4e38f, b2 = 3.4e38f, b3 = 3.4e38f;
    for (int s = 0; s < N/16; ++s) {
        int j = s * 16;                          // uniform sample -> broadcast load
        float d = dist2(q, vb[j]);
        if (j == i) d = 3.4e38f;
        float t0 = fminf(b0, d); float r = fmaxf(b0, d); b0 = t0;
        float t1 = fminf(b1, r); r = fmaxf(b1, r); b1 = t1;
        float t2 = fminf(b2, r); r = fmaxf(b2, r); b2 = t2;
        b3 = fminf(b3, r);
    }
    thr[b*N + i] = b3;                           // 4th-smallest sampled distance
}

// ------------------------------------------------- filtered candidate append
// cand layout: [query][chunk][SLOTS]; each (query,chunk) owned by ONE thread -> no atomics
__global__ void k_append(const float4* __restrict__ vb4, const float* __restrict__ thr,
                         int* __restrict__ ccnt, int* __restrict__ cand) {
    __shared__ float4 pts[CH];
    int b = blockIdx.z, qg = blockIdx.x, c = blockIdx.y;
    const float4* vb = vb4 + b * N;
    int base = c * CH;
    for (int t = threadIdx.x; t < CH; t += 256) pts[t] = vb[base + t];
    __syncthreads();
    int i = qg * QG + threadIdx.x;
    int qi = b*N + i;
    float4 q = vb[i];
    float t0 = thr[qi];
    int* mycand = cand + ((size_t)qi * NCH + c) * SLOTS;
    int p = 0;
#pragma unroll 4
    for (int j = 0; j < CH; ++j) {
        float d = dist2(q, pts[j]);              // broadcast LDS read
        int gj = base + j;
        if (d <= t0 && gj != i) {
            if (p < SLOTS) mycand[p] = gj;       // fire-and-forget store, reg counter
            p++;
        }
    }
    ccnt[qi * NCH + c] = p;                      // actual count (>SLOTS flags overflow)
}

// ------------------------------------------------- exact top-16 from candidates
__global__ void k_select(const float4* __restrict__ vb4, const int* __restrict__ ccnt,
                         const int* __restrict__ cand, int* __restrict__ idxout,
                         int* __restrict__ fbcnt, int* __restrict__ fblist) {
    int b = blockIdx.y;
    int i = blockIdx.x * 256 + threadIdx.x;
    int qi = b*N + i;
    int cc[NCH];
    int total = 0, mx = 0;
#pragma unroll
    for (int c = 0; c < NCH; ++c) {
        cc[c] = ccnt[qi * NCH + c];
        total += cc[c];
        mx = max(mx, cc[c]);
    }
    if (total < KNN || mx > SLOTS) {             // rare: defer to wave-per-query kernel
        int p = atomicAdd(fbcnt, 1);
        fblist[p] = qi;
        return;
    }
    const float4* vb = vb4 + b * N;
    float4 q = vb[i];
    const int* mycand = cand + (size_t)qi * CAP;
    DECL16;
#pragma unroll 1
    for (int c = 0; c < NCH; ++c) {
        int nc = cc[c];
        const int* cp = mycand + c * SLOTS;
        if (nc > 0) {
            int jn = cp[0];
            float4 vn = vb[jn];
            for (int p = 0; p < nc; ++p) {
                int j = jn; float4 v = vn;
                if (p + 1 < nc) { jn = cp[p+1]; vn = vb[jn]; }   // prefetch under the chain
                float d = dist2(q, v);
                ull nk = ((ull)__float_as_uint(d) << 32) | (unsigned)j;
                INS16(nk);
            }
        }
    }
    int* oi = idxout + (size_t)qi * KNN;
    oi[0]=(int)(K0&0xffffffffu);  oi[1]=(int)(K1&0xffffffffu);
    oi[2]=(int)(K2&0xffffffffu);  oi[3]=(int)(K3&0xffffffffu);
    oi[4]=(int)(K4&0xffffffffu);  oi[5]=(int)(K5&0xffffffffu);
    oi[6]=(int)(K6&0xffffffffu);  oi[7]=(int)(K7&0xffffffffu);
    oi[8]=(int)(K8&0xffffffffu);  oi[9]=(int)(K9&0xffffffffu);
    oi[10]=(int)(K10&0xffffffffu); oi[11]=(int)(K11&0xffffffffu);
    oi[12]=(int)(K12&0xffffffffu); oi[13]=(int)(K13&0xffffffffu);
    oi[14]=(int)(K14&0xffffffffu); oi[15]=(int)(K15&0xffffffffu);
}

// ------------------------------------------------- exact wave-per-query fallback
__global__ void k_fallback(const float4* __restrict__ vb4, const int* __restrict__ fbcnt,
                           const int* __restrict__ fblist, int* __restrict__ idxout) {
    __shared__ ull heap[64*16];
    int nfb = *fbcnt;
    int lane = threadIdx.x;
    for (int w = blockIdx.x; w < nfb; w += gridDim.x) {
        int qi = fblist[w];
        int b = qi >> 13, i = qi & (N-1);
        const float4* vb = vb4 + b * N;
        float4 q = vb[i];
        DECL16;
        for (int j = lane; j < N; j += 64) {
            if (j == i) continue;
            float d = dist2(q, vb[j]);
            ull nk = ((ull)__float_as_uint(d) << 32) | (unsigned)j;
            INS16(nk);
        }
        heap[lane*16+0]=K0;   heap[lane*16+1]=K1;   heap[lane*16+2]=K2;   heap[lane*16+3]=K3;
        heap[lane*16+4]=K4;   heap[lane*16+5]=K5;   heap[lane*16+6]=K6;   heap[lane*16+7]=K7;
        heap[lane*16+8]=K8;   heap[lane*16+9]=K9;   heap[lane*16+10]=K10; heap[lane*16+11]=K11;
        heap[lane*16+12]=K12; heap[lane*16+13]=K13; heap[lane*16+14]=K14; heap[lane*16+15]=K15;
        __syncthreads();
        int ptr = 0;
        int* oi = idxout + (size_t)qi * KNN;
        for (int r = 0; r < KNN; ++r) {          // 16-round tournament merge
            ull h = (ptr < 16) ? heap[lane*16 + ptr] : ~0ull;
            ull m = h;
#pragma unroll
            for (int s = 1; s < 64; s <<= 1) {
                ull o = __shfl_xor(m, s, 64);
                m = (o < m) ? o : m;
            }
            if (h == m && m != ~0ull) ptr++;
            if (lane == r) oi[r] = (int)(m & 0xffffffffu);
        }
        __syncthreads();
    }
}

// ------------------------------------------------- graph conv feature (n,128)
__global__ void k_feature(const float4* __restrict__ vb4, const float4* __restrict__ sup4,
                          const int* __restrict__ idx, float* __restrict__ feat) {
    int b = blockIdx.y, i = blockIdx.x;
    __shared__ float4 dirn[KNN];
    const float4* vb = vb4 + b * N;
    if (threadIdx.x < KNN) {
        int j = idx[(size_t)(b*N + i)*KNN + threadIdx.x];
        float4 q = vb[i], p = vb[j];
        float dx = p.x - q.x, dy = p.y - q.y, dz = p.z - q.z;
        float inv = 1.f / fmaxf(sqrtf(fmaf(dx, dx, fmaf(dy, dy, dz*dz))), 1e-12f);
        dirn[threadIdx.x] = make_float4(dx*inv, dy*inv, dz*inv, 0.f);
    }
    __syncthreads();
    int k = threadIdx.x;
    float acc = 0.f;
#pragma unroll
    for (int s = 0; s < SUP; ++s) {
        float4 sv = sup4[s*KC + k];
        float m = 0.f;                            // relu folded into max
#pragma unroll
        for (int K = 0; K < KNN; ++K) {
            float4 dn = dirn[K];
            float t = fmaf(dn.x, sv.x, fmaf(dn.y, sv.y, dn.z*sv.z));
            m = fmaxf(m, t);
        }
        acc += m;
    }
    feat[(size_t)(b*N + i)*KC + k] = acc * (1.f/SUP);
}

// ------------------------------------------------- neighbor-max + partial mean
__global__ void k_nbmax(const float* __restrict__ feat, const int* __restrict__ idx,
                        float* __restrict__ partial) {
    int b = blockIdx.y;
    int p0 = blockIdx.x * PPB;
    int k = threadIdx.x;
    const float* fb = feat + (size_t)b*N*KC;
    float sum = 0.f;
    for (int p = 0; p < PPB; ++p) {
        const int* ii = idx + (size_t)(b*N + p0 + p) * KNN;
        float m = -3.4e38f;
#pragma unroll
        for (int K = 0; K < KNN; ++K)
            m = fmaxf(m, fb[(size_t)ii[K]*KC + k]);
        sum += m;
    }
    partial[(size_t)(b*(N/PPB) + blockIdx.x)*KC + k] = sum;
}

// ------------------------------------------------- global vec + W2 fold
__global__ void k_global(const float* __restrict__ partial, const float* __restrict__ wconv,
                         float* __restrict__ gconst) {
    int b = blockIdx.x, k = threadIdx.x;
    float s = 0.f;
    for (int q = 0; q < N/PPB; ++q) s += partial[(size_t)(b*(N/PPB) + q)*KC + k];
    __shared__ float fg[KC];
    fg[k] = s * (1.f/N);
    __syncthreads();
    float acc = 0.f;
    for (int c = 0; c < KC; ++c)
        acc = fmaf(fg[c], wconv[k*2*KC + KC + c], acc);
    gconst[b*KC + k] = acc;
}

// ------------------------------------------------- epilogue GEMM + STE + add
__global__ void k_out(const float* __restrict__ feat, const float4* __restrict__ wt4,
                      const float4* __restrict__ wste4, const float4* __restrict__ vb4,
                      const float* __restrict__ gconst, float* __restrict__ out) {
    int p0 = blockIdx.x * OPB;
    int k = threadIdx.x;
    float acc[OPB];
#pragma unroll
    for (int p = 0; p < OPB; ++p) acc[p] = 0.f;
#pragma unroll 4
    for (int c4 = 0; c4 < KC/4; ++c4) {
        float4 w = wt4[c4*KC + k];
#pragma unroll
        for (int p = 0; p < OPB; ++p) {
            const float4 f = *(const float4*)(feat + (size_t)(p0 + p)*KC + c4*4);
            acc[p] = fmaf(f.x, w.x, fmaf(f.y, w.y, fmaf(f.z, w.z, fmaf(f.w, w.w, acc[p]))));
        }
    }
    float4 ws = wste4[k];
#pragma unroll
    for (int p = 0; p < OPB; ++p) {
        int pt = p0 + p;
        int b = pt >> 13;                        // / N
        float4 v = vb4[pt];
        float fste = fmaf(v.x, ws.x, fmaf(v.y, ws.y, v.z*ws.z));
        out[(size_t)pt*KC + k] = acc[p] + gconst[b*KC + k] + feat[(size_t)pt*KC + k] + fste;
    }
}

extern "C" void kernel_launch(void* const* d_in, const int* in_sizes, int n_in,
                              void* d_out, int out_size, void* d_ws, size_t ws_size,
                              hipStream_t stream) {
    const float* verts = (const float*)d_in[0];
    const float* dirs  = (const float*)d_in[1];
    const float* wste  = (const float*)d_in[2];
    const float* wconv = (const float*)d_in[3];
    float* out = (float*)d_out;

    // workspace layout (floats); cand is dead after select/fallback and aliased as feat
    float* ws = (float*)d_ws;
    float4* vb4   = (float4*)ws;                  // BS*N
    float4* sup4  = vb4 + BS*N;                   // SK
    float4* wste4 = sup4 + SK;                    // KC
    float4* wt4   = wste4 + KC;                   // 32*KC
    float*  thr   = (float*)(wt4 + 32*KC);        // BS*N
    int*    ccnt  = (int*)(thr + BS*N);           // BS*N*NCH
    int*    fbcnt = ccnt + BS*N*NCH;              // 16 (use [0])
    int*    fblist= fbcnt + 16;                   // BS*N
    int*    cand  = fblist + BS*N;                // BS*N*CAP
    float*  feat  = (float*)cand;                 // BS*N*KC  (alias: same size)
    int*    idx   = cand + (size_t)BS*N*CAP;      // BS*N*KNN
    float*  partial = (float*)(idx + (size_t)BS*N*KNN);  // BS*(N/PPB)*KC
    float*  gconst  = partial + (size_t)BS*(N/PPB)*KC;   // BS*KC

    hipMemsetAsync(fbcnt, 0, 16*sizeof(int), stream);   // only fbcnt (ccnt fully written)
    k_prep<<<(BS*N + SK + KC + 32*KC + 255)/256, 256, 0, stream>>>(verts, dirs, wste, wconv,
                                                                   vb4, sup4, wste4, wt4);
    k_thr<<<dim3(N/256, BS), 256, 0, stream>>>(vb4, thr);
    k_append<<<dim3(N/QG, NCH, BS), 256, 0, stream>>>(vb4, thr, ccnt, cand);
    k_select<<<dim3(N/256, BS), 256, 0, stream>>>(vb4, ccnt, cand, idx, fbcnt, fblist);
    k_fallback<<<2048, 64, 0, stream>>>(vb4, fbcnt, fblist, idx);
    k_feature<<<dim3(N, BS), KC, 0, stream>>>(vb4, sup4, idx, feat);
    k_nbmax<<<dim3(N/PPB, BS), KC, 0, stream>>>(feat, idx, partial);
    k_global<<<BS, KC, 0, stream>>>(partial, wconv, gconst);
    k_out<<<BS*N/OPB, KC, 0, stream>>>(feat, wt4, wste4, vb4, gconst, out);
}

// Round 4
// 416.521 us; speedup vs baseline: 4.4832x; 1.1945x over previous
//
#include <hip/hip_runtime.h>
#include <math.h>

#define N     8192
#define BS    2
#define KNN   16
#define SUP   7
#define KC    128
#define SK    (SUP*KC)   // 896
#define NCH   8
#define CH    (N/NCH)    // 1024
#define SLOTS 16
#define CAP   (NCH*SLOTS) // 128
#define QG    256
#define PPB   64
#define OPB   8

typedef unsigned long long ull;

__device__ __forceinline__ float dist2(float4 a, float4 b) {
    float dx = a.x - b.x, dy = a.y - b.y, dz = a.z - b.z;
    return fmaf(dx, dx, fmaf(dy, dy, dz * dz));
}

// sorted-insert chain over 16 NAMED u64 registers (guaranteed no scratch)
#define SW(Kt) { ull _lo = (Kt < _n) ? Kt : _n; ull _hi = (Kt < _n) ? _n : Kt; Kt = _lo; _n = _hi; }
#define INS16(NK) do { ull _n = (NK); if (_n < K15) { \
    SW(K0) SW(K1) SW(K2) SW(K3) SW(K4) SW(K5) SW(K6) SW(K7) \
    SW(K8) SW(K9) SW(K10) SW(K11) SW(K12) SW(K13) SW(K14) SW(K15) } } while(0)

#define DECL16 ull K0=~0ull,K1=~0ull,K2=~0ull,K3=~0ull,K4=~0ull,K5=~0ull,K6=~0ull,K7=~0ull, \
                   K8=~0ull,K9=~0ull,K10=~0ull,K11=~0ull,K12=~0ull,K13=~0ull,K14=~0ull,K15=~0ull;

// ---------------------------------------------------------------- prep
__global__ void k_prep(const float* __restrict__ verts, const float* __restrict__ dirs,
                       const float* __restrict__ wste, const float* __restrict__ wconv,
                       float4* __restrict__ vb4, float4* __restrict__ sup4,
                       float4* __restrict__ wste4, float4* __restrict__ wt4) {
    int t = blockIdx.x * blockDim.x + threadIdx.x;
    if (t < BS * N)
        vb4[t] = make_float4(verts[t*3], verts[t*3+1], verts[t*3+2], 0.f);
    int u = t - BS * N;
    if (u >= 0 && u < SK) {
        float x = dirs[u], y = dirs[SK + u], z = dirs[2*SK + u];
        float inv = 1.f / fmaxf(sqrtf(fmaf(x, x, fmaf(y, y, z*z))), 1e-12f);
        sup4[u] = make_float4(x*inv, y*inv, z*inv, 0.f);
    }
    int v = u - SK;
    if (v >= 0 && v < KC)
        wste4[v] = make_float4(wste[v*3], wste[v*3+1], wste[v*3+2], 0.f);
    int w = v - KC;
    if (w >= 0 && w < 32*KC) {
        int c4 = w >> 7, k = w & 127;
        const float* r = wconv + k*2*KC + c4*4;   // W1 half, transposed to [c4][k]
        wt4[w] = make_float4(r[0], r[1], r[2], r[3]);
    }
}

// ------------------------------------------------- calibrated per-query radius
// phase A: t4 = 4th-smallest over every-16th sample (512 pts)
// phase B: c  = count of every-4th sample (2048 pts) with d<=t4, 4 threads/query
// thr = t4 * (12/c)^(2/3)  -> targets E[#pass over full N] ~ 48 (3D volume law)
__global__ void k_thr(const float4* __restrict__ vb4, float* __restrict__ thr) {
    int b = blockIdx.y;
    int i = blockIdx.x * 64 + (threadIdx.x >> 2);
    int sub = threadIdx.x & 3;
    const float4* vb = vb4 + b * N;
    float4 q = vb[i];
    float b0 = 3.4e38f, b1 = 3.4e38f, b2 = 3.4e38f, b3 = 3.4e38f;
#pragma unroll 4
    for (int s = 0; s < N/16; ++s) {
        int j = s * 16;                          // broadcast load
        float d = dist2(q, vb[j]);
        if (j == i) d = 3.4e38f;
        float t0 = fminf(b0, d); float r = fmaxf(b0, d); b0 = t0;
        float t1 = fminf(b1, r); r = fmaxf(b1, r); b1 = t1;
        float t2 = fminf(b2, r); r = fmaxf(b2, r); b2 = t2;
        b3 = fminf(b3, r);
    }
    float t4 = b3;
    int c = 0;
#pragma unroll 4
    for (int s = 0; s < N/16; ++s) {
        int j = s * 16 + sub * 4;                // every-4th overall across subs
        float d = dist2(q, vb[j]);
        c += (d <= t4 && j != i) ? 1 : 0;
    }
    c += __shfl_xor(c, 1, 64);
    c += __shfl_xor(c, 2, 64);                   // c >= 4 guaranteed
    if (sub == 0) {
        float f = __powf(12.0f / (float)c, 0.6666667f);
        thr[b*N + i] = t4 * f;
    }
}

// ------------------------------------------------- filtered candidate append
// cand layout: [query][chunk][SLOTS]; each (query,chunk) owned by ONE thread -> no atomics
__global__ void k_append(const float4* __restrict__ vb4, const float* __restrict__ thr,
                         int* __restrict__ ccnt, int* __restrict__ cand) {
    __shared__ float4 pts[CH];
    int b = blockIdx.z, qg = blockIdx.x, c = blockIdx.y;
    const float4* vb = vb4 + b * N;
    int base = c * CH;
    for (int t = threadIdx.x; t < CH; t += 256) pts[t] = vb[base + t];
    __syncthreads();
    int i = qg * QG + threadIdx.x;
    int qi = b*N + i;
    float4 q = vb[i];
    float t0 = thr[qi];
    int* mycand = cand + ((size_t)qi * NCH + c) * SLOTS;
    int p = 0;
#pragma unroll 4
    for (int j = 0; j < CH; ++j) {
        float d = dist2(q, pts[j]);              // broadcast LDS read
        int gj = base + j;
        if (d <= t0 && gj != i) {
            if (p < SLOTS) mycand[p] = gj;       // fire-and-forget store, reg counter
            p++;
        }
    }
    ccnt[qi * NCH + c] = p;                      // actual count (>SLOTS flags overflow)
}

// ------------------------------------------------- exact top-16 from candidates
__global__ void k_select(const float4* __restrict__ vb4, const int* __restrict__ ccnt,
                         const int* __restrict__ cand, int* __restrict__ idxout,
                         int* __restrict__ fbcnt, int* __restrict__ fblist) {
    int b = blockIdx.y;
    int i = blockIdx.x * 256 + threadIdx.x;
    int qi = b*N + i;
    int cc[NCH];
    int total = 0, mx = 0;
#pragma unroll
    for (int c = 0; c < NCH; ++c) {
        cc[c] = ccnt[qi * NCH + c];
        total += cc[c];
        mx = max(mx, cc[c]);
    }
    if (total < KNN || mx > SLOTS) {             // rare: defer to wave-per-query kernel
        int p = atomicAdd(fbcnt, 1);
        fblist[p] = qi;
        return;
    }
    const float4* vb = vb4 + b * N;
    float4 q = vb[i];
    const int* mycand = cand + (size_t)qi * CAP;
    DECL16;
#pragma unroll 1
    for (int c = 0; c < NCH; ++c) {
        int nc = cc[c];
        const int* cp = mycand + c * SLOTS;
        if (nc > 0) {
            int jn = cp[0];
            float4 vn = vb[jn];
            for (int p = 0; p < nc; ++p) {
                int j = jn; float4 v = vn;
                if (p + 1 < nc) { jn = cp[p+1]; vn = vb[jn]; }   // prefetch under the chain
                float d = dist2(q, v);
                ull nk = ((ull)__float_as_uint(d) << 32) | (unsigned)j;
                INS16(nk);
            }
        }
    }
    int* oi = idxout + (size_t)qi * KNN;
    oi[0]=(int)(K0&0xffffffffu);  oi[1]=(int)(K1&0xffffffffu);
    oi[2]=(int)(K2&0xffffffffu);  oi[3]=(int)(K3&0xffffffffu);
    oi[4]=(int)(K4&0xffffffffu);  oi[5]=(int)(K5&0xffffffffu);
    oi[6]=(int)(K6&0xffffffffu);  oi[7]=(int)(K7&0xffffffffu);
    oi[8]=(int)(K8&0xffffffffu);  oi[9]=(int)(K9&0xffffffffu);
    oi[10]=(int)(K10&0xffffffffu); oi[11]=(int)(K11&0xffffffffu);
    oi[12]=(int)(K12&0xffffffffu); oi[13]=(int)(K13&0xffffffffu);
    oi[14]=(int)(K14&0xffffffffu); oi[15]=(int)(K15&0xffffffffu);
}

// ------------------------------------------------- exact wave-per-query fallback
__global__ void k_fallback(const float4* __restrict__ vb4, const int* __restrict__ fbcnt,
                           const int* __restrict__ fblist, int* __restrict__ idxout) {
    __shared__ ull heap[64*16];
    int nfb = *fbcnt;
    int lane = threadIdx.x;
    for (int w = blockIdx.x; w < nfb; w += gridDim.x) {
        int qi = fblist[w];
        int b = qi >> 13, i = qi & (N-1);
        const float4* vb = vb4 + b * N;
        float4 q = vb[i];
        DECL16;
        for (int j = lane; j < N; j += 64) {
            if (j == i) continue;
            float d = dist2(q, vb[j]);
            ull nk = ((ull)__float_as_uint(d) << 32) | (unsigned)j;
            INS16(nk);
        }
        heap[lane*16+0]=K0;   heap[lane*16+1]=K1;   heap[lane*16+2]=K2;   heap[lane*16+3]=K3;
        heap[lane*16+4]=K4;   heap[lane*16+5]=K5;   heap[lane*16+6]=K6;   heap[lane*16+7]=K7;
        heap[lane*16+8]=K8;   heap[lane*16+9]=K9;   heap[lane*16+10]=K10; heap[lane*16+11]=K11;
        heap[lane*16+12]=K12; heap[lane*16+13]=K13; heap[lane*16+14]=K14; heap[lane*16+15]=K15;
        __syncthreads();
        int ptr = 0;
        int* oi = idxout + (size_t)qi * KNN;
        for (int r = 0; r < KNN; ++r) {          // 16-round tournament merge
            ull h = (ptr < 16) ? heap[lane*16 + ptr] : ~0ull;
            ull m = h;
#pragma unroll
            for (int s = 1; s < 64; s <<= 1) {
                ull o = __shfl_xor(m, s, 64);
                m = (o < m) ? o : m;
            }
            if (h == m && m != ~0ull) ptr++;
            if (lane == r) oi[r] = (int)(m & 0xffffffffu);
        }
        __syncthreads();
    }
}

// ------------------------------------------------- graph conv feature (n,128)
__global__ void k_feature(const float4* __restrict__ vb4, const float4* __restrict__ sup4,
                          const int* __restrict__ idx, float* __restrict__ feat) {
    int b = blockIdx.y, i = blockIdx.x;
    __shared__ float4 dirn[KNN];
    const float4* vb = vb4 + b * N;
    if (threadIdx.x < KNN) {
        int j = idx[(size_t)(b*N + i)*KNN + threadIdx.x];
        float4 q = vb[i], p = vb[j];
        float dx = p.x - q.x, dy = p.y - q.y, dz = p.z - q.z;
        float inv = 1.f / fmaxf(sqrtf(fmaf(dx, dx, fmaf(dy, dy, dz*dz))), 1e-12f);
        dirn[threadIdx.x] = make_float4(dx*inv, dy*inv, dz*inv, 0.f);
    }
    __syncthreads();
    int k = threadIdx.x;
    float acc = 0.f;
#pragma unroll
    for (int s = 0; s < SUP; ++s) {
        float4 sv = sup4[s*KC + k];
        float m = 0.f;                            // relu folded into max
#pragma unroll
        for (int K = 0; K < KNN; ++K) {
            float4 dn = dirn[K];
            float t = fmaf(dn.x, sv.x, fmaf(dn.y, sv.y, dn.z*sv.z));
            m = fmaxf(m, t);
        }
        acc += m;
    }
    feat[(size_t)(b*N + i)*KC + k] = acc * (1.f/SUP);
}

// ------------------------------------------------- neighbor-max + partial mean
__global__ void k_nbmax(const float* __restrict__ feat, const int* __restrict__ idx,
                        float* __restrict__ partial) {
    int b = blockIdx.y;
    int p0 = blockIdx.x * PPB;
    int k = threadIdx.x;
    const float* fb = feat + (size_t)b*N*KC;
    float sum = 0.f;
    for (int p = 0; p < PPB; ++p) {
        const int* ii = idx + (size_t)(b*N + p0 + p) * KNN;
        float m = -3.4e38f;
#pragma unroll
        for (int K = 0; K < KNN; ++K)
            m = fmaxf(m, fb[(size_t)ii[K]*KC + k]);
        sum += m;
    }
    partial[(size_t)(b*(N/PPB) + blockIdx.x)*KC + k] = sum;
}

// ------------------------------------------------- global vec + W2 fold
__global__ void k_global(const float* __restrict__ partial, const float* __restrict__ wconv,
                         float* __restrict__ gconst) {
    int b = blockIdx.x, k = threadIdx.x;
    float s = 0.f;
    for (int q = 0; q < N/PPB; ++q) s += partial[(size_t)(b*(N/PPB) + q)*KC + k];
    __shared__ float fg[KC];
    fg[k] = s * (1.f/N);
    __syncthreads();
    float acc = 0.f;
    for (int c = 0; c < KC; ++c)
        acc = fmaf(fg[c], wconv[k*2*KC + KC + c], acc);
    gconst[b*KC + k] = acc;
}

// ------------------------------------------------- epilogue GEMM + STE + add
__global__ void k_out(const float* __restrict__ feat, const float4* __restrict__ wt4,
                      const float4* __restrict__ wste4, const float4* __restrict__ vb4,
                      const float* __restrict__ gconst, float* __restrict__ out) {
    int p0 = blockIdx.x * OPB;
    int k = threadIdx.x;
    float acc[OPB];
#pragma unroll
    for (int p = 0; p < OPB; ++p) acc[p] = 0.f;
#pragma unroll 4
    for (int c4 = 0; c4 < KC/4; ++c4) {
        float4 w = wt4[c4*KC + k];
#pragma unroll
        for (int p = 0; p < OPB; ++p) {
            const float4 f = *(const float4*)(feat + (size_t)(p0 + p)*KC + c4*4);
            acc[p] = fmaf(f.x, w.x, fmaf(f.y, w.y, fmaf(f.z, w.z, fmaf(f.w, w.w, acc[p]))));
        }
    }
    float4 ws = wste4[k];
#pragma unroll
    for (int p = 0; p < OPB; ++p) {
        int pt = p0 + p;
        int b = pt >> 13;                        // / N
        float4 v = vb4[pt];
        float fste = fmaf(v.x, ws.x, fmaf(v.y, ws.y, v.z*ws.z));
        out[(size_t)pt*KC + k] = acc[p] + gconst[b*KC + k] + feat[(size_t)pt*KC + k] + fste;
    }
}

extern "C" void kernel_launch(void* const* d_in, const int* in_sizes, int n_in,
                              void* d_out, int out_size, void* d_ws, size_t ws_size,
                              hipStream_t stream) {
    const float* verts = (const float*)d_in[0];
    const float* dirs  = (const float*)d_in[1];
    const float* wste  = (const float*)d_in[2];
    const float* wconv = (const float*)d_in[3];
    float* out = (float*)d_out;

    // workspace layout (floats); cand is dead after select/fallback and aliased as feat
    float* ws = (float*)d_ws;
    float4* vb4   = (float4*)ws;                  // BS*N
    float4* sup4  = vb4 + BS*N;                   // SK
    float4* wste4 = sup4 + SK;                    // KC
    float4* wt4   = wste4 + KC;                   // 32*KC
    float*  thr   = (float*)(wt4 + 32*KC);        // BS*N
    int*    ccnt  = (int*)(thr + BS*N);           // BS*N*NCH
    int*    fbcnt = ccnt + BS*N*NCH;              // 16 (use [0])
    int*    fblist= fbcnt + 16;                   // BS*N
    int*    cand  = fblist + BS*N;                // BS*N*CAP
    float*  feat  = (float*)cand;                 // BS*N*KC  (alias: same size)
    int*    idx   = cand + (size_t)BS*N*CAP;      // BS*N*KNN
    float*  partial = (float*)(idx + (size_t)BS*N*KNN);  // BS*(N/PPB)*KC
    float*  gconst  = partial + (size_t)BS*(N/PPB)*KC;   // BS*KC

    hipMemsetAsync(fbcnt, 0, 16*sizeof(int), stream);   // only fbcnt (ccnt fully written)
    k_prep<<<(BS*N + SK + KC + 32*KC + 255)/256, 256, 0, stream>>>(verts, dirs, wste, wconv,
                                                                   vb4, sup4, wste4, wt4);
    k_thr<<<dim3(N/64, BS), 256, 0, stream>>>(vb4, thr);
    k_append<<<dim3(N/QG, NCH, BS), 256, 0, stream>>>(vb4, thr, ccnt, cand);
    k_select<<<dim3(N/256, BS), 256, 0, stream>>>(vb4, ccnt, cand, idx, fbcnt, fblist);
    k_fallback<<<2048, 64, 0, stream>>>(vb4, fbcnt, fblist, idx);
    k_feature<<<dim3(N, BS), KC, 0, stream>>>(vb4, sup4, idx, feat);
    k_nbmax<<<dim3(N/PPB, BS), KC, 0, stream>>>(feat, idx, partial);
    k_global<<<BS, KC, 0, stream>>>(partial, wconv, gconst);
    k_out<<<BS*N/OPB, KC, 0, stream>>>(feat, wt4, wste4, vb4, gconst, out);
}

// Round 5
// 402.593 us; speedup vs baseline: 4.6383x; 1.0346x over previous
//
#include <hip/hip_runtime.h>
#include <math.h>

#define N     8192
#define BS    2
#define KNN   16
#define SUP   7
#define KC    128
#define SK    (SUP*KC)   // 896
#define NCH   16
#define CH    (N/NCH)    // 512
#define SLOTS 12
#define CAP   (NCH*SLOTS) // 192
#define QG    256
#define PPB   64
#define OPB   8

typedef unsigned long long ull;

__device__ __forceinline__ float dist2(float4 a, float4 b) {
    float dx = a.x - b.x, dy = a.y - b.y, dz = a.z - b.z;
    return fmaf(dx, dx, fmaf(dy, dy, dz * dz));
}

// sorted-insert chain over 16 NAMED u64 registers (guaranteed no scratch)
#define SW(Kt) { ull _lo = (Kt < _n) ? Kt : _n; ull _hi = (Kt < _n) ? _n : Kt; Kt = _lo; _n = _hi; }
#define INS16(NK) do { ull _n = (NK); if (_n < K15) { \
    SW(K0) SW(K1) SW(K2) SW(K3) SW(K4) SW(K5) SW(K6) SW(K7) \
    SW(K8) SW(K9) SW(K10) SW(K11) SW(K12) SW(K13) SW(K14) SW(K15) } } while(0)

#define DECL16 ull K0=~0ull,K1=~0ull,K2=~0ull,K3=~0ull,K4=~0ull,K5=~0ull,K6=~0ull,K7=~0ull, \
                   K8=~0ull,K9=~0ull,K10=~0ull,K11=~0ull,K12=~0ull,K13=~0ull,K14=~0ull,K15=~0ull;

// ---------------------------------------------------------------- prep
__global__ void k_prep(const float* __restrict__ verts, const float* __restrict__ dirs,
                       const float* __restrict__ wste, const float* __restrict__ wconv,
                       float4* __restrict__ vb4, float4* __restrict__ sup4,
                       float4* __restrict__ wste4, float4* __restrict__ wt4) {
    int t = blockIdx.x * blockDim.x + threadIdx.x;
    if (t < BS * N)
        vb4[t] = make_float4(verts[t*3], verts[t*3+1], verts[t*3+2], 0.f);
    int u = t - BS * N;
    if (u >= 0 && u < SK) {
        float x = dirs[u], y = dirs[SK + u], z = dirs[2*SK + u];
        float inv = 1.f / fmaxf(sqrtf(fmaf(x, x, fmaf(y, y, z*z))), 1e-12f);
        sup4[u] = make_float4(x*inv, y*inv, z*inv, 0.f);
    }
    int v = u - SK;
    if (v >= 0 && v < KC)
        wste4[v] = make_float4(wste[v*3], wste[v*3+1], wste[v*3+2], 0.f);
    int w = v - KC;
    if (w >= 0 && w < 32*KC) {
        int c4 = w >> 7, k = w & 127;
        const float* r = wconv + k*2*KC + c4*4;   // W1 half, transposed to [c4][k]
        wt4[w] = make_float4(r[0], r[1], r[2], r[3]);
    }
}

// ------------------------------------------------- calibrated per-query radius
// phase A: t4 = 4th-smallest over every-16th sample (512 pts)
// phase B: c  = count of every-4th sample (2048 pts) with d<=t4, 4 threads/query
// thr = t4 * (12/c)^(2/3)  -> targets E[#pass over full N] ~ 48 (3D volume law)
__global__ void k_thr(const float4* __restrict__ vb4, float* __restrict__ thr) {
    int b = blockIdx.y;
    int i = blockIdx.x * 64 + (threadIdx.x >> 2);
    int sub = threadIdx.x & 3;
    const float4* vb = vb4 + b * N;
    float4 q = vb[i];
    float b0 = 3.4e38f, b1 = 3.4e38f, b2 = 3.4e38f, b3 = 3.4e38f;
#pragma unroll 4
    for (int s = 0; s < N/16; ++s) {
        int j = s * 16;                          // uniform -> scalar load
        float d = dist2(q, vb[j]);
        if (j == i) d = 3.4e38f;
        float t0 = fminf(b0, d); float r = fmaxf(b0, d); b0 = t0;
        float t1 = fminf(b1, r); r = fmaxf(b1, r); b1 = t1;
        float t2 = fminf(b2, r); r = fmaxf(b2, r); b2 = t2;
        b3 = fminf(b3, r);
    }
    float t4 = b3;
    int c = 0;
#pragma unroll 4
    for (int s = 0; s < N/16; ++s) {
        int j = s * 16 + sub * 4;                // every-4th overall across subs
        float d = dist2(q, vb[j]);
        c += (d <= t4 && j != i) ? 1 : 0;
    }
    c += __shfl_xor(c, 1, 64);
    c += __shfl_xor(c, 2, 64);                   // c >= 4 guaranteed
    if (sub == 0) {
        float f = __powf(12.0f / (float)c, 0.6666667f);
        thr[b*N + i] = t4 * f;
    }
}

// ------------------------------------------------- filtered candidate append
// cand layout: [query][chunk][SLOTS]; each (query,chunk) owned by ONE thread -> no atomics.
// Point address is wave-uniform -> scalar-pipe loads; no LDS staging, no barriers.
__global__ void k_append(const float4* __restrict__ vb4, const float* __restrict__ thr,
                         int* __restrict__ ccnt, int* __restrict__ cand) {
    int b = blockIdx.z, qg = blockIdx.x, c = blockIdx.y;
    const float4* vb = vb4 + b * N;
    int base = c * CH;
    int i = qg * QG + threadIdx.x;
    int qi = b*N + i;
    float4 q = vb[i];
    float t0 = thr[qi];
    int* mycand = cand + ((size_t)qi * NCH + c) * SLOTS;
    const float4* pts = vb + base;
    int p = 0;
#pragma unroll 8
    for (int j = 0; j < CH; ++j) {
        float d = dist2(q, pts[j]);              // wave-uniform address
        int gj = base + j;
        if (d <= t0 && gj != i) {
            if (p < SLOTS) mycand[p] = gj;       // fire-and-forget store, reg counter
            p++;
        }
    }
    ccnt[qi * NCH + c] = p;                      // actual count (>SLOTS flags overflow)
}

// ------------------------------------------------- exact top-16 from candidates
__global__ void k_select(const float4* __restrict__ vb4, const int* __restrict__ ccnt,
                         const int* __restrict__ cand, int* __restrict__ idxout,
                         int* __restrict__ fbcnt, int* __restrict__ fblist) {
    int b = blockIdx.y;
    int i = blockIdx.x * 256 + threadIdx.x;
    int qi = b*N + i;
    int cc[NCH];
    int total = 0, mx = 0;
#pragma unroll
    for (int c4 = 0; c4 < NCH/4; ++c4) {
        int4 v = *(const int4*)(ccnt + qi*NCH + c4*4);
        cc[c4*4+0] = v.x; cc[c4*4+1] = v.y; cc[c4*4+2] = v.z; cc[c4*4+3] = v.w;
        total += v.x + v.y + v.z + v.w;
        mx = max(mx, max(max(v.x, v.y), max(v.z, v.w)));
    }
    if (total < KNN || mx > SLOTS) {             // rare: defer to wave-per-query kernel
        int p = atomicAdd(fbcnt, 1);
        fblist[p] = qi;
        return;
    }
    const float4* vb = vb4 + b * N;
    float4 q = vb[i];
    const int* mycand = cand + (size_t)qi * CAP;
    DECL16;
#pragma unroll                                   // FULL unroll: cc[] indices compile-time
    for (int c = 0; c < NCH; ++c) {
        int nc = cc[c];
        const int* cp = mycand + c * SLOTS;
        if (nc > 0) {
            int jn = cp[0];
            float4 vn = vb[jn];
            for (int p = 0; p < nc; ++p) {
                int j = jn; float4 v = vn;
                if (p + 1 < nc) { jn = cp[p+1]; vn = vb[jn]; }   // prefetch under the chain
                float d = dist2(q, v);
                ull nk = ((ull)__float_as_uint(d) << 32) | (unsigned)j;
                INS16(nk);
            }
        }
    }
    int* oi = idxout + (size_t)qi * KNN;
    oi[0]=(int)(K0&0xffffffffu);  oi[1]=(int)(K1&0xffffffffu);
    oi[2]=(int)(K2&0xffffffffu);  oi[3]=(int)(K3&0xffffffffu);
    oi[4]=(int)(K4&0xffffffffu);  oi[5]=(int)(K5&0xffffffffu);
    oi[6]=(int)(K6&0xffffffffu);  oi[7]=(int)(K7&0xffffffffu);
    oi[8]=(int)(K8&0xffffffffu);  oi[9]=(int)(K9&0xffffffffu);
    oi[10]=(int)(K10&0xffffffffu); oi[11]=(int)(K11&0xffffffffu);
    oi[12]=(int)(K12&0xffffffffu); oi[13]=(int)(K13&0xffffffffu);
    oi[14]=(int)(K14&0xffffffffu); oi[15]=(int)(K15&0xffffffffu);
}

// ------------------------------------------------- exact wave-per-query fallback
__global__ void k_fallback(const float4* __restrict__ vb4, const int* __restrict__ fbcnt,
                           const int* __restrict__ fblist, int* __restrict__ idxout) {
    __shared__ ull heap[64*16];
    int nfb = *fbcnt;
    int lane = threadIdx.x;
    for (int w = blockIdx.x; w < nfb; w += gridDim.x) {
        int qi = fblist[w];
        int b = qi >> 13, i = qi & (N-1);
        const float4* vb = vb4 + b * N;
        float4 q = vb[i];
        DECL16;
        for (int j = lane; j < N; j += 64) {
            if (j == i) continue;
            float d = dist2(q, vb[j]);
            ull nk = ((ull)__float_as_uint(d) << 32) | (unsigned)j;
            INS16(nk);
        }
        heap[lane*16+0]=K0;   heap[lane*16+1]=K1;   heap[lane*16+2]=K2;   heap[lane*16+3]=K3;
        heap[lane*16+4]=K4;   heap[lane*16+5]=K5;   heap[lane*16+6]=K6;   heap[lane*16+7]=K7;
        heap[lane*16+8]=K8;   heap[lane*16+9]=K9;   heap[lane*16+10]=K10; heap[lane*16+11]=K11;
        heap[lane*16+12]=K12; heap[lane*16+13]=K13; heap[lane*16+14]=K14; heap[lane*16+15]=K15;
        __syncthreads();
        int ptr = 0;
        int* oi = idxout + (size_t)qi * KNN;
        for (int r = 0; r < KNN; ++r) {          // 16-round tournament merge
            ull h = (ptr < 16) ? heap[lane*16 + ptr] : ~0ull;
            ull m = h;
#pragma unroll
            for (int s = 1; s < 64; s <<= 1) {
                ull o = __shfl_xor(m, s, 64);
                m = (o < m) ? o : m;
            }
            if (h == m && m != ~0ull) ptr++;
            if (lane == r) oi[r] = (int)(m & 0xffffffffu);
        }
        __syncthreads();
    }
}

// ------------------------------------------------- graph conv feature (n,128)
__global__ void k_feature(const float4* __restrict__ vb4, const float4* __restrict__ sup4,
                          const int* __restrict__ idx, float* __restrict__ feat) {
    int b = blockIdx.y, i = blockIdx.x;
    __shared__ float4 dirn[KNN];
    const float4* vb = vb4 + b * N;
    if (threadIdx.x < KNN) {
        int j = idx[(size_t)(b*N + i)*KNN + threadIdx.x];
        float4 q = vb[i], p = vb[j];
        float dx = p.x - q.x, dy = p.y - q.y, dz = p.z - q.z;
        float inv = 1.f / fmaxf(sqrtf(fmaf(dx, dx, fmaf(dy, dy, dz*dz))), 1e-12f);
        dirn[threadIdx.x] = make_float4(dx*inv, dy*inv, dz*inv, 0.f);
    }
    __syncthreads();
    int k = threadIdx.x;
    float acc = 0.f;
#pragma unroll
    for (int s = 0; s < SUP; ++s) {
        float4 sv = sup4[s*KC + k];
        float m = 0.f;                            // relu folded into max
#pragma unroll
        for (int K = 0; K < KNN; ++K) {
            float4 dn = dirn[K];
            float t = fmaf(dn.x, sv.x, fmaf(dn.y, sv.y, dn.z*sv.z));
            m = fmaxf(m, t);
        }
        acc += m;
    }
    feat[(size_t)(b*N + i)*KC + k] = acc * (1.f/SUP);
}

// ------------------------------------------------- neighbor-max + partial mean
__global__ void k_nbmax(const float* __restrict__ feat, const int* __restrict__ idx,
                        float* __restrict__ partial) {
    int b = blockIdx.y;
    int p0 = blockIdx.x * PPB;
    int k = threadIdx.x;
    const float* fb = feat + (size_t)b*N*KC;
    float sum = 0.f;
    for (int p = 0; p < PPB; ++p) {
        const int* ii = idx + (size_t)(b*N + p0 + p) * KNN;
        float m = -3.4e38f;
#pragma unroll
        for (int K = 0; K < KNN; ++K)
            m = fmaxf(m, fb[(size_t)ii[K]*KC + k]);
        sum += m;
    }
    partial[(size_t)(b*(N/PPB) + blockIdx.x)*KC + k] = sum;
}

// ------------------------------------------------- global vec + W2 fold
__global__ void k_global(const float* __restrict__ partial, const float* __restrict__ wconv,
                         float* __restrict__ gconst) {
    int b = blockIdx.x, k = threadIdx.x;
    float s = 0.f;
    for (int q = 0; q < N/PPB; ++q) s += partial[(size_t)(b*(N/PPB) + q)*KC + k];
    __shared__ float fg[KC];
    fg[k] = s * (1.f/N);
    __syncthreads();
    float acc = 0.f;
    for (int c = 0; c < KC; ++c)
        acc = fmaf(fg[c], wconv[k*2*KC + KC + c], acc);
    gconst[b*KC + k] = acc;
}

// ------------------------------------------------- epilogue GEMM + STE + add
__global__ void k_out(const float* __restrict__ feat, const float4* __restrict__ wt4,
                      const float4* __restrict__ wste4, const float4* __restrict__ vb4,
                      const float* __restrict__ gconst, float* __restrict__ out) {
    int p0 = blockIdx.x * OPB;
    int k = threadIdx.x;
    float acc[OPB];
#pragma unroll
    for (int p = 0; p < OPB; ++p) acc[p] = 0.f;
#pragma unroll 4
    for (int c4 = 0; c4 < KC/4; ++c4) {
        float4 w = wt4[c4*KC + k];
#pragma unroll
        for (int p = 0; p < OPB; ++p) {
            const float4 f = *(const float4*)(feat + (size_t)(p0 + p)*KC + c4*4);
            acc[p] = fmaf(f.x, w.x, fmaf(f.y, w.y, fmaf(f.z, w.z, fmaf(f.w, w.w, acc[p]))));
        }
    }
    float4 ws = wste4[k];
#pragma unroll
    for (int p = 0; p < OPB; ++p) {
        int pt = p0 + p;
        int b = pt >> 13;                        // / N
        float4 v = vb4[pt];
        float fste = fmaf(v.x, ws.x, fmaf(v.y, ws.y, v.z*ws.z));
        out[(size_t)pt*KC + k] = acc[p] + gconst[b*KC + k] + feat[(size_t)pt*KC + k] + fste;
    }
}

extern "C" void kernel_launch(void* const* d_in, const int* in_sizes, int n_in,
                              void* d_out, int out_size, void* d_ws, size_t ws_size,
                              hipStream_t stream) {
    const float* verts = (const float*)d_in[0];
    const float* dirs  = (const float*)d_in[1];
    const float* wste  = (const float*)d_in[2];
    const float* wconv = (const float*)d_in[3];
    float* out = (float*)d_out;

    // workspace layout (floats); cand is dead after select/fallback and aliased as feat
    float* ws = (float*)d_ws;
    float4* vb4   = (float4*)ws;                  // BS*N
    float4* sup4  = vb4 + BS*N;                   // SK
    float4* wste4 = sup4 + SK;                    // KC
    float4* wt4   = wste4 + KC;                   // 32*KC
    float*  thr   = (float*)(wt4 + 32*KC);        // BS*N
    int*    ccnt  = (int*)(thr + BS*N);           // BS*N*NCH
    int*    fbcnt = ccnt + BS*N*NCH;              // 16 (use [0])
    int*    fblist= fbcnt + 16;                   // BS*N
    int*    cand  = fblist + BS*N;                // BS*N*CAP
    float*  feat  = (float*)cand;                 // BS*N*KC  (alias: CAP>=KC, fits)
    int*    idx   = cand + (size_t)BS*N*CAP;      // BS*N*KNN
    float*  partial = (float*)(idx + (size_t)BS*N*KNN);  // BS*(N/PPB)*KC
    float*  gconst  = partial + (size_t)BS*(N/PPB)*KC;   // BS*KC

    hipMemsetAsync(fbcnt, 0, 16*sizeof(int), stream);   // only fbcnt (ccnt fully written)
    k_prep<<<(BS*N + SK + KC + 32*KC + 255)/256, 256, 0, stream>>>(verts, dirs, wste, wconv,
                                                                   vb4, sup4, wste4, wt4);
    k_thr<<<dim3(N/64, BS), 256, 0, stream>>>(vb4, thr);
    k_append<<<dim3(N/QG, NCH, BS), 256, 0, stream>>>(vb4, thr, ccnt, cand);
    k_select<<<dim3(N/256, BS), 256, 0, stream>>>(vb4, ccnt, cand, idx, fbcnt, fblist);
    k_fallback<<<2048, 64, 0, stream>>>(vb4, fbcnt, fblist, idx);
    k_feature<<<dim3(N, BS), KC, 0, stream>>>(vb4, sup4, idx, feat);
    k_nbmax<<<dim3(N/PPB, BS), KC, 0, stream>>>(feat, idx, partial);
    k_global<<<BS, KC, 0, stream>>>(partial, wconv, gconst);
    k_out<<<BS*N/OPB, KC, 0, stream>>>(feat, wt4, wste4, vb4, gconst, out);
}

// Round 6
// 378.053 us; speedup vs baseline: 4.9394x; 1.0649x over previous
//
#include <hip/hip_runtime.h>
#include <math.h>

#define N     8192
#define BS    2
#define KNN   16
#define SUP   7
#define KC    128
#define SK    (SUP*KC)   // 896
#define NCH   16
#define CH    (N/NCH)    // 512
#define SLOTS 12
#define CAP   (NCH*SLOTS) // 192
#define QG    256
#define PPB   64
#define OPB   8

typedef unsigned long long ull;

__device__ __forceinline__ float dist2(float4 a, float4 b) {
    float dx = a.x - b.x, dy = a.y - b.y, dz = a.z - b.z;
    return fmaf(dx, dx, fmaf(dy, dy, dz * dz));
}

// sorted-insert chain over 16 NAMED u64 registers (guaranteed no scratch)
#define SW(Kt) { ull _lo = (Kt < _n) ? Kt : _n; ull _hi = (Kt < _n) ? _n : Kt; Kt = _lo; _n = _hi; }
#define INS16(NK) do { ull _n = (NK); if (_n < K15) { \
    SW(K0) SW(K1) SW(K2) SW(K3) SW(K4) SW(K5) SW(K6) SW(K7) \
    SW(K8) SW(K9) SW(K10) SW(K11) SW(K12) SW(K13) SW(K14) SW(K15) } } while(0)

#define DECL16 ull K0=~0ull,K1=~0ull,K2=~0ull,K3=~0ull,K4=~0ull,K5=~0ull,K6=~0ull,K7=~0ull, \
                   K8=~0ull,K9=~0ull,K10=~0ull,K11=~0ull,K12=~0ull,K13=~0ull,K14=~0ull,K15=~0ull;

// ---------------------------------------------------------------- prep
__global__ void k_prep(const float* __restrict__ verts, const float* __restrict__ dirs,
                       const float* __restrict__ wste, const float* __restrict__ wconv,
                       float4* __restrict__ vb4, float4* __restrict__ sup4,
                       float4* __restrict__ wste4, float4* __restrict__ wt4) {
    int t = blockIdx.x * blockDim.x + threadIdx.x;
    if (t < BS * N)
        vb4[t] = make_float4(verts[t*3], verts[t*3+1], verts[t*3+2], 0.f);
    int u = t - BS * N;
    if (u >= 0 && u < SK) {
        float x = dirs[u], y = dirs[SK + u], z = dirs[2*SK + u];
        float inv = 1.f / fmaxf(sqrtf(fmaf(x, x, fmaf(y, y, z*z))), 1e-12f);
        sup4[u] = make_float4(x*inv, y*inv, z*inv, 0.f);
    }
    int v = u - SK;
    if (v >= 0 && v < KC)
        wste4[v] = make_float4(wste[v*3], wste[v*3+1], wste[v*3+2], 0.f);
    int w = v - KC;
    if (w >= 0 && w < 32*KC) {
        int c4 = w >> 7, k = w & 127;
        const float* r = wconv + k*2*KC + c4*4;   // W1 half, transposed to [c4][k]
        wt4[w] = make_float4(r[0], r[1], r[2], r[3]);
    }
}

// ------------------------------------------------- calibrated per-query radius
// phase A: t4 = 4th-smallest over every-16th sample (512 pts)
// phase B: c  = count of every-4th sample (2048 pts) with d<=t4, 4 threads/query
// thr = t4 * (12/c)^(2/3)  -> targets E[#pass over full N] ~ 48 (3D volume law)
__global__ void k_thr(const float4* __restrict__ vb4, float* __restrict__ thr) {
    int b = blockIdx.y;
    int i = blockIdx.x * 64 + (threadIdx.x >> 2);
    int sub = threadIdx.x & 3;
    const float4* vb = vb4 + b * N;
    float4 q = vb[i];
    float b0 = 3.4e38f, b1 = 3.4e38f, b2 = 3.4e38f, b3 = 3.4e38f;
#pragma unroll 4
    for (int s = 0; s < N/16; ++s) {
        int j = s * 16;                          // uniform -> scalar load
        float d = dist2(q, vb[j]);
        if (j == i) d = 3.4e38f;
        float t0 = fminf(b0, d); float r = fmaxf(b0, d); b0 = t0;
        float t1 = fminf(b1, r); r = fmaxf(b1, r); b1 = t1;
        float t2 = fminf(b2, r); r = fmaxf(b2, r); b2 = t2;
        b3 = fminf(b3, r);
    }
    float t4 = b3;
    int c = 0;
#pragma unroll 4
    for (int s = 0; s < N/16; ++s) {
        int j = s * 16 + sub * 4;                // every-4th overall across subs
        float d = dist2(q, vb[j]);
        c += (d <= t4 && j != i) ? 1 : 0;
    }
    c += __shfl_xor(c, 1, 64);
    c += __shfl_xor(c, 2, 64);                   // c >= 4 guaranteed
    if (sub == 0) {
        float f = __powf(12.0f / (float)c, 0.6666667f);
        thr[b*N + i] = t4 * f;
    }
}

// ------------------------------------------------- filtered candidate append
// cand layout: [query][chunk][SLOTS]; each (query,chunk) owned by ONE thread -> no atomics.
// Point address is wave-uniform -> scalar-pipe loads; no LDS staging, no barriers.
__global__ void k_append(const float4* __restrict__ vb4, const float* __restrict__ thr,
                         int* __restrict__ ccnt, int* __restrict__ cand) {
    int b = blockIdx.z, qg = blockIdx.x, c = blockIdx.y;
    const float4* vb = vb4 + b * N;
    int base = c * CH;
    int i = qg * QG + threadIdx.x;
    int qi = b*N + i;
    float4 q = vb[i];
    float t0 = thr[qi];
    int* mycand = cand + ((size_t)qi * NCH + c) * SLOTS;
    const float4* pts = vb + base;
    int p = 0;
#pragma unroll 8
    for (int j = 0; j < CH; ++j) {
        float d = dist2(q, pts[j]);              // wave-uniform address
        int gj = base + j;
        if (d <= t0 && gj != i) {
            if (p < SLOTS) mycand[p] = gj;       // fire-and-forget store, reg counter
            p++;
        }
    }
    ccnt[qi * NCH + c] = p;                      // actual count (>SLOTS flags overflow)
}

// ------------------------------------------------- exact top-16 from candidates
// Batched-MLP: all 12 slots of a chunk loaded & gathered UNCONDITIONALLY
// (masked by slot<nc; stale-garbage idx clamped with &(N-1) for address safety),
// so ~12 gathers are in flight instead of a 1-deep dependent chain.
__global__ void k_select(const float4* __restrict__ vb4, const int* __restrict__ ccnt,
                         const int* __restrict__ cand, int* __restrict__ idxout,
                         int* __restrict__ fbcnt, int* __restrict__ fblist) {
    int b = blockIdx.y;
    int i = blockIdx.x * 64 + threadIdx.x;
    int qi = b*N + i;
    int cc[NCH];
    int total = 0, mx = 0;
#pragma unroll
    for (int c4 = 0; c4 < NCH/4; ++c4) {
        int4 v = *(const int4*)(ccnt + qi*NCH + c4*4);
        cc[c4*4+0] = v.x; cc[c4*4+1] = v.y; cc[c4*4+2] = v.z; cc[c4*4+3] = v.w;
        total += v.x + v.y + v.z + v.w;
        mx = max(mx, max(max(v.x, v.y), max(v.z, v.w)));
    }
    if (total < KNN || mx > SLOTS) {             // rare: defer to wave-per-query kernel
        int p = atomicAdd(fbcnt, 1);
        fblist[p] = qi;
        return;
    }
    const float4* vb = vb4 + b * N;
    float4 q = vb[i];
    const int* mycand = cand + (size_t)qi * CAP;
    DECL16;
#pragma unroll                                   // FULL unroll: cc[] indices compile-time
    for (int c = 0; c < NCH; ++c) {
        int nc = cc[c];
        const int* cp = mycand + c * SLOTS;
        int4 i0 = *(const int4*)(cp + 0);        // 3 independent 16B idx loads
        int4 i1 = *(const int4*)(cp + 4);
        int4 i2 = *(const int4*)(cp + 8);
        int j[12] = { i0.x, i0.y, i0.z, i0.w, i1.x, i1.y, i1.z, i1.w,
                      i2.x, i2.y, i2.z, i2.w };
        float4 pv[12];
#pragma unroll
        for (int s = 0; s < 12; ++s)
            pv[s] = vb[j[s] & (N-1)];            // 12 independent gathers (clamped addr)
#pragma unroll
        for (int s = 0; s < 12; ++s) {
            float d = dist2(q, pv[s]);
            ull nk = (s < nc)
                   ? (((ull)__float_as_uint(d) << 32) | (unsigned)j[s])
                   : ~0ull;                       // invalid -> never passes < K15
            INS16(nk);
        }
    }
    int* oi = idxout + (size_t)qi * KNN;
    oi[0]=(int)(K0&0xffffffffu);  oi[1]=(int)(K1&0xffffffffu);
    oi[2]=(int)(K2&0xffffffffu);  oi[3]=(int)(K3&0xffffffffu);
    oi[4]=(int)(K4&0xffffffffu);  oi[5]=(int)(K5&0xffffffffu);
    oi[6]=(int)(K6&0xffffffffu);  oi[7]=(int)(K7&0xffffffffu);
    oi[8]=(int)(K8&0xffffffffu);  oi[9]=(int)(K9&0xffffffffu);
    oi[10]=(int)(K10&0xffffffffu); oi[11]=(int)(K11&0xffffffffu);
    oi[12]=(int)(K12&0xffffffffu); oi[13]=(int)(K13&0xffffffffu);
    oi[14]=(int)(K14&0xffffffffu); oi[15]=(int)(K15&0xffffffffu);
}

// ------------------------------------------------- exact wave-per-query fallback
__global__ void k_fallback(const float4* __restrict__ vb4, const int* __restrict__ fbcnt,
                           const int* __restrict__ fblist, int* __restrict__ idxout) {
    __shared__ ull heap[64*16];
    int nfb = *fbcnt;
    int lane = threadIdx.x;
    for (int w = blockIdx.x; w < nfb; w += gridDim.x) {
        int qi = fblist[w];
        int b = qi >> 13, i = qi & (N-1);
        const float4* vb = vb4 + b * N;
        float4 q = vb[i];
        DECL16;
        for (int j = lane; j < N; j += 64) {
            if (j == i) continue;
            float d = dist2(q, vb[j]);
            ull nk = ((ull)__float_as_uint(d) << 32) | (unsigned)j;
            INS16(nk);
        }
        heap[lane*16+0]=K0;   heap[lane*16+1]=K1;   heap[lane*16+2]=K2;   heap[lane*16+3]=K3;
        heap[lane*16+4]=K4;   heap[lane*16+5]=K5;   heap[lane*16+6]=K6;   heap[lane*16+7]=K7;
        heap[lane*16+8]=K8;   heap[lane*16+9]=K9;   heap[lane*16+10]=K10; heap[lane*16+11]=K11;
        heap[lane*16+12]=K12; heap[lane*16+13]=K13; heap[lane*16+14]=K14; heap[lane*16+15]=K15;
        __syncthreads();
        int ptr = 0;
        int* oi = idxout + (size_t)qi * KNN;
        for (int r = 0; r < KNN; ++r) {          // 16-round tournament merge
            ull h = (ptr < 16) ? heap[lane*16 + ptr] : ~0ull;
            ull m = h;
#pragma unroll
            for (int s = 1; s < 64; s <<= 1) {
                ull o = __shfl_xor(m, s, 64);
                m = (o < m) ? o : m;
            }
            if (h == m && m != ~0ull) ptr++;
            if (lane == r) oi[r] = (int)(m & 0xffffffffu);
        }
        __syncthreads();
    }
}

// ------------------------------------------------- graph conv feature (n,128)
__global__ void k_feature(const float4* __restrict__ vb4, const float4* __restrict__ sup4,
                          const int* __restrict__ idx, float* __restrict__ feat) {
    int b = blockIdx.y, i = blockIdx.x;
    __shared__ float4 dirn[KNN];
    const float4* vb = vb4 + b * N;
    if (threadIdx.x < KNN) {
        int j = idx[(size_t)(b*N + i)*KNN + threadIdx.x];
        float4 q = vb[i], p = vb[j];
        float dx = p.x - q.x, dy = p.y - q.y, dz = p.z - q.z;
        float inv = 1.f / fmaxf(sqrtf(fmaf(dx, dx, fmaf(dy, dy, dz*dz))), 1e-12f);
        dirn[threadIdx.x] = make_float4(dx*inv, dy*inv, dz*inv, 0.f);
    }
    __syncthreads();
    int k = threadIdx.x;
    float acc = 0.f;
#pragma unroll
    for (int s = 0; s < SUP; ++s) {
        float4 sv = sup4[s*KC + k];
        float m = 0.f;                            // relu folded into max
#pragma unroll
        for (int K = 0; K < KNN; ++K) {
            float4 dn = dirn[K];
            float t = fmaf(dn.x, sv.x, fmaf(dn.y, sv.y, dn.z*sv.z));
            m = fmaxf(m, t);
        }
        acc += m;
    }
    feat[(size_t)(b*N + i)*KC + k] = acc * (1.f/SUP);
}

// ------------------------------------------------- neighbor-max + partial mean
__global__ void k_nbmax(const float* __restrict__ feat, const int* __restrict__ idx,
                        float* __restrict__ partial) {
    int b = blockIdx.y;
    int p0 = blockIdx.x * PPB;
    int k = threadIdx.x;
    const float* fb = feat + (size_t)b*N*KC;
    float sum = 0.f;
    for (int p = 0; p < PPB; ++p) {
        const int* ii = idx + (size_t)(b*N + p0 + p) * KNN;
        float m = -3.4e38f;
#pragma unroll
        for (int K = 0; K < KNN; ++K)
            m = fmaxf(m, fb[(size_t)ii[K]*KC + k]);
        sum += m;
    }
    partial[(size_t)(b*(N/PPB) + blockIdx.x)*KC + k] = sum;
}

// ------------------------------------------------- global vec + W2 fold
__global__ void k_global(const float* __restrict__ partial, const float* __restrict__ wconv,
                         float* __restrict__ gconst) {
    int b = blockIdx.x, k = threadIdx.x;
    float s = 0.f;
    for (int q = 0; q < N/PPB; ++q) s += partial[(size_t)(b*(N/PPB) + q)*KC + k];
    __shared__ float fg[KC];
    fg[k] = s * (1.f/N);
    __syncthreads();
    float acc = 0.f;
    for (int c = 0; c < KC; ++c)
        acc = fmaf(fg[c], wconv[k*2*KC + KC + c], acc);
    gconst[b*KC + k] = acc;
}

// ------------------------------------------------- epilogue GEMM + STE + add
__global__ void k_out(const float* __restrict__ feat, const float4* __restrict__ wt4,
                      const float4* __restrict__ wste4, const float4* __restrict__ vb4,
                      const float* __restrict__ gconst, float* __restrict__ out) {
    int p0 = blockIdx.x * OPB;
    int k = threadIdx.x;
    float acc[OPB];
#pragma unroll
    for (int p = 0; p < OPB; ++p) acc[p] = 0.f;
#pragma unroll 4
    for (int c4 = 0; c4 < KC/4; ++c4) {
        float4 w = wt4[c4*KC + k];
#pragma unroll
        for (int p = 0; p < OPB; ++p) {
            const float4 f = *(const float4*)(feat + (size_t)(p0 + p)*KC + c4*4);
            acc[p] = fmaf(f.x, w.x, fmaf(f.y, w.y, fmaf(f.z, w.z, fmaf(f.w, w.w, acc[p]))));
        }
    }
    float4 ws = wste4[k];
#pragma unroll
    for (int p = 0; p < OPB; ++p) {
        int pt = p0 + p;
        int b = pt >> 13;                        // / N
        float4 v = vb4[pt];
        float fste = fmaf(v.x, ws.x, fmaf(v.y, ws.y, v.z*ws.z));
        out[(size_t)pt*KC + k] = acc[p] + gconst[b*KC + k] + feat[(size_t)pt*KC + k] + fste;
    }
}

extern "C" void kernel_launch(void* const* d_in, const int* in_sizes, int n_in,
                              void* d_out, int out_size, void* d_ws, size_t ws_size,
                              hipStream_t stream) {
    const float* verts = (const float*)d_in[0];
    const float* dirs  = (const float*)d_in[1];
    const float* wste  = (const float*)d_in[2];
    const float* wconv = (const float*)d_in[3];
    float* out = (float*)d_out;

    // workspace layout (floats); cand is dead after select/fallback and aliased as feat
    float* ws = (float*)d_ws;
    float4* vb4   = (float4*)ws;                  // BS*N
    float4* sup4  = vb4 + BS*N;                   // SK
    float4* wste4 = sup4 + SK;                    // KC
    float4* wt4   = wste4 + KC;                   // 32*KC
    float*  thr   = (float*)(wt4 + 32*KC);        // BS*N
    int*    ccnt  = (int*)(thr + BS*N);           // BS*N*NCH
    int*    fbcnt = ccnt + BS*N*NCH;              // 16 (use [0])
    int*    fblist= fbcnt + 16;                   // BS*N
    int*    cand  = fblist + BS*N;                // BS*N*CAP
    float*  feat  = (float*)cand;                 // BS*N*KC  (alias: CAP>=KC, fits)
    int*    idx   = cand + (size_t)BS*N*CAP;      // BS*N*KNN
    float*  partial = (float*)(idx + (size_t)BS*N*KNN);  // BS*(N/PPB)*KC
    float*  gconst  = partial + (size_t)BS*(N/PPB)*KC;   // BS*KC

    hipMemsetAsync(fbcnt, 0, 16*sizeof(int), stream);   // only fbcnt (ccnt fully written)
    k_prep<<<(BS*N + SK + KC + 32*KC + 255)/256, 256, 0, stream>>>(verts, dirs, wste, wconv,
                                                                   vb4, sup4, wste4, wt4);
    k_thr<<<dim3(N/64, BS), 256, 0, stream>>>(vb4, thr);
    k_append<<<dim3(N/QG, NCH, BS), 256, 0, stream>>>(vb4, thr, ccnt, cand);
    k_select<<<dim3(N/64, BS), 64, 0, stream>>>(vb4, ccnt, cand, idx, fbcnt, fblist);
    k_fallback<<<2048, 64, 0, stream>>>(vb4, fbcnt, fblist, idx);
    k_feature<<<dim3(N, BS), KC, 0, stream>>>(vb4, sup4, idx, feat);
    k_nbmax<<<dim3(N/PPB, BS), KC, 0, stream>>>(feat, idx, partial);
    k_global<<<BS, KC, 0, stream>>>(partial, wconv, gconst);
    k_out<<<BS*N/OPB, KC, 0, stream>>>(feat, wt4, wste4, vb4, gconst, out);
}

// Round 7
// 357.497 us; speedup vs baseline: 5.2234x; 1.0575x over previous
//
#include <hip/hip_runtime.h>
#include <math.h>

#define N     8192
#define BS    2
#define KNN   16
#define SUP   7
#define KC    128
#define SK    (SUP*KC)   // 896
#define NCH   16
#define CH    (N/NCH)    // 512
#define SLOTS 24
#define CAP   (NCH*SLOTS) // 384 u16 slots = 768B/query
#define QG    256
#define PPB   64
#define OPB   8

typedef unsigned long long ull;
typedef unsigned short ushort8 __attribute__((ext_vector_type(8)));

__device__ __forceinline__ float dist2(float4 a, float4 b) {
    float dx = a.x - b.x, dy = a.y - b.y, dz = a.z - b.z;
    return fmaf(dx, dx, fmaf(dy, dy, dz * dz));
}

// sorted-insert chain over 16 NAMED u64 registers (guaranteed no scratch)
#define SW(Kt) { ull _lo = (Kt < _n) ? Kt : _n; ull _hi = (Kt < _n) ? _n : Kt; Kt = _lo; _n = _hi; }
#define INS16(NK) do { ull _n = (NK); if (_n < K15) { \
    SW(K0) SW(K1) SW(K2) SW(K3) SW(K4) SW(K5) SW(K6) SW(K7) \
    SW(K8) SW(K9) SW(K10) SW(K11) SW(K12) SW(K13) SW(K14) SW(K15) } } while(0)

#define DECL16 ull K0=~0ull,K1=~0ull,K2=~0ull,K3=~0ull,K4=~0ull,K5=~0ull,K6=~0ull,K7=~0ull, \
                   K8=~0ull,K9=~0ull,K10=~0ull,K11=~0ull,K12=~0ull,K13=~0ull,K14=~0ull,K15=~0ull;

// ---------------------------------------------------------------- prep
__global__ void k_prep(const float* __restrict__ verts, const float* __restrict__ dirs,
                       const float* __restrict__ wste, const float* __restrict__ wconv,
                       float4* __restrict__ vb4, float4* __restrict__ sup4,
                       float4* __restrict__ wste4, float4* __restrict__ wt4) {
    int t = blockIdx.x * blockDim.x + threadIdx.x;
    if (t < BS * N)
        vb4[t] = make_float4(verts[t*3], verts[t*3+1], verts[t*3+2], 0.f);
    int u = t - BS * N;
    if (u >= 0 && u < SK) {
        float x = dirs[u], y = dirs[SK + u], z = dirs[2*SK + u];
        float inv = 1.f / fmaxf(sqrtf(fmaf(x, x, fmaf(y, y, z*z))), 1e-12f);
        sup4[u] = make_float4(x*inv, y*inv, z*inv, 0.f);
    }
    int v = u - SK;
    if (v >= 0 && v < KC)
        wste4[v] = make_float4(wste[v*3], wste[v*3+1], wste[v*3+2], 0.f);
    int w = v - KC;
    if (w >= 0 && w < 32*KC) {
        int c4 = w >> 7, k = w & 127;
        const float* r = wconv + k*2*KC + c4*4;   // W1 half, transposed to [c4][k]
        wt4[w] = make_float4(r[0], r[1], r[2], r[3]);
    }
}

// ------------------------------------------------- calibrated per-query radius
// phase A: t4 = 4th-smallest over every-16th sample (512 pts)
// phase B: c  = count of every-4th sample (2048 pts) with d<=t4, 4 threads/query
// thr = t4 * (12/c)^(2/3)  -> targets E[#pass over full N] ~ 48 (3D volume law)
__global__ void k_thr(const float4* __restrict__ vb4, float* __restrict__ thr) {
    int b = blockIdx.y;
    int i = blockIdx.x * 64 + (threadIdx.x >> 2);
    int sub = threadIdx.x & 3;
    const float4* vb = vb4 + b * N;
    float4 q = vb[i];
    float b0 = 3.4e38f, b1 = 3.4e38f, b2 = 3.4e38f, b3 = 3.4e38f;
#pragma unroll 4
    for (int s = 0; s < N/16; ++s) {
        int j = s * 16;                          // uniform -> scalar load
        float d = dist2(q, vb[j]);
        if (j == i) d = 3.4e38f;
        float t0 = fminf(b0, d); float r = fmaxf(b0, d); b0 = t0;
        float t1 = fminf(b1, r); r = fmaxf(b1, r); b1 = t1;
        float t2 = fminf(b2, r); r = fmaxf(b2, r); b2 = t2;
        b3 = fminf(b3, r);
    }
    float t4 = b3;
    int c = 0;
#pragma unroll 4
    for (int s = 0; s < N/16; ++s) {
        int j = s * 16 + sub * 4;                // every-4th overall across subs
        float d = dist2(q, vb[j]);
        c += (d <= t4 && j != i) ? 1 : 0;
    }
    c += __shfl_xor(c, 1, 64);
    c += __shfl_xor(c, 2, 64);                   // c >= 4 guaranteed
    if (sub == 0) {
        float f = __powf(12.0f / (float)c, 0.6666667f);
        thr[b*N + i] = t4 * f;
    }
}

// ------------------------------------------------- filtered candidate append
// cand layout: [query][chunk][SLOTS] u16; each (query,chunk) owned by ONE thread.
__global__ void k_append(const float4* __restrict__ vb4, const float* __restrict__ thr,
                         int* __restrict__ ccnt, unsigned short* __restrict__ cand) {
    int b = blockIdx.z, qg = blockIdx.x, c = blockIdx.y;
    const float4* vb = vb4 + b * N;
    int base = c * CH;
    int i = qg * QG + threadIdx.x;
    int qi = b*N + i;
    float4 q = vb[i];
    float t0 = thr[qi];
    unsigned short* mycand = cand + ((size_t)qi * NCH + c) * SLOTS;
    const float4* pts = vb + base;
    int p = 0;
#pragma unroll 8
    for (int j = 0; j < CH; ++j) {
        float d = dist2(q, pts[j]);              // wave-uniform address -> scalar pipe
        int gj = base + j;
        if (d <= t0 && gj != i) {
            if (p < SLOTS) mycand[p] = (unsigned short)gj;
            p++;
        }
    }
    ccnt[qi * NCH + c] = p;                      // actual count (>SLOTS flags overflow)
}

// ------------------------------------------------- exact top-16 from candidates
// Runtime chunk loop (small code: fits I$). Per chunk: group-of-8 u16 idx loads,
// branch-gated by nc (99.6% of chunks touch only group 0); 8 independent gathers
// per group, then masked insert-chain. Garbage slots clamped with &(N-1).
#define GRP8(GV, SOFF) { \
    int jj[8]; \
    _Pragma("unroll") for (int s = 0; s < 8; ++s) jj[s] = (int)GV[s]; \
    float4 pv[8]; \
    _Pragma("unroll") for (int s = 0; s < 8; ++s) pv[s] = vb[jj[s] & (N-1)]; \
    _Pragma("unroll") for (int s = 0; s < 8; ++s) { \
        float d = dist2(q, pv[s]); \
        ull nk = ((SOFF + s) < nc) \
               ? (((ull)__float_as_uint(d) << 32) | (unsigned)jj[s]) : ~0ull; \
        INS16(nk); \
    } }

__global__ void k_select(const float4* __restrict__ vb4, const int* __restrict__ ccnt,
                         const unsigned short* __restrict__ cand, int* __restrict__ idxout,
                         int* __restrict__ fbcnt, int* __restrict__ fblist) {
    int b = blockIdx.y;
    int i = blockIdx.x * 64 + threadIdx.x;
    int qi = b*N + i;
    int total = 0, mx = 0;
#pragma unroll
    for (int c4 = 0; c4 < NCH/4; ++c4) {
        int4 v = *(const int4*)(ccnt + qi*NCH + c4*4);
        total += v.x + v.y + v.z + v.w;
        mx = max(mx, max(max(v.x, v.y), max(v.z, v.w)));
    }
    if (total < KNN || mx > SLOTS) {             // astronomically rare now
        int p = atomicAdd(fbcnt, 1);
        fblist[p] = qi;
        return;
    }
    const float4* vb = vb4 + b * N;
    float4 q = vb[i];
    const unsigned short* mycand = cand + (size_t)qi * CAP;
    DECL16;
#pragma unroll 1
    for (int c = 0; c < NCH; ++c) {
        int nc = ccnt[qi * NCH + c];             // L1-resident reload (compile-time regs)
        const unsigned short* cp = mycand + c * SLOTS;
        ushort8 g0 = *(const ushort8*)cp;
        GRP8(g0, 0);
        if (nc > 8)  { ushort8 g1 = *(const ushort8*)(cp + 8);  GRP8(g1, 8); }
        if (nc > 16) { ushort8 g2 = *(const ushort8*)(cp + 16); GRP8(g2, 16); }
    }
    int* oi = idxout + (size_t)qi * KNN;
    oi[0]=(int)(K0&0xffffffffu);  oi[1]=(int)(K1&0xffffffffu);
    oi[2]=(int)(K2&0xffffffffu);  oi[3]=(int)(K3&0xffffffffu);
    oi[4]=(int)(K4&0xffffffffu);  oi[5]=(int)(K5&0xffffffffu);
    oi[6]=(int)(K6&0xffffffffu);  oi[7]=(int)(K7&0xffffffffu);
    oi[8]=(int)(K8&0xffffffffu);  oi[9]=(int)(K9&0xffffffffu);
    oi[10]=(int)(K10&0xffffffffu); oi[11]=(int)(K11&0xffffffffu);
    oi[12]=(int)(K12&0xffffffffu); oi[13]=(int)(K13&0xffffffffu);
    oi[14]=(int)(K14&0xffffffffu); oi[15]=(int)(K15&0xffffffffu);
}

// ------------------------------------------------- exact wave-per-query fallback
__global__ void k_fallback(const float4* __restrict__ vb4, const int* __restrict__ fbcnt,
                           const int* __restrict__ fblist, int* __restrict__ idxout) {
    __shared__ ull heap[64*16];
    int nfb = *fbcnt;
    int lane = threadIdx.x;
    for (int w = blockIdx.x; w < nfb; w += gridDim.x) {
        int qi = fblist[w];
        int b = qi >> 13, i = qi & (N-1);
        const float4* vb = vb4 + b * N;
        float4 q = vb[i];
        DECL16;
        for (int j = lane; j < N; j += 64) {
            if (j == i) continue;
            float d = dist2(q, vb[j]);
            ull nk = ((ull)__float_as_uint(d) << 32) | (unsigned)j;
            INS16(nk);
        }
        heap[lane*16+0]=K0;   heap[lane*16+1]=K1;   heap[lane*16+2]=K2;   heap[lane*16+3]=K3;
        heap[lane*16+4]=K4;   heap[lane*16+5]=K5;   heap[lane*16+6]=K6;   heap[lane*16+7]=K7;
        heap[lane*16+8]=K8;   heap[lane*16+9]=K9;   heap[lane*16+10]=K10; heap[lane*16+11]=K11;
        heap[lane*16+12]=K12; heap[lane*16+13]=K13; heap[lane*16+14]=K14; heap[lane*16+15]=K15;
        __syncthreads();
        int ptr = 0;
        int* oi = idxout + (size_t)qi * KNN;
        for (int r = 0; r < KNN; ++r) {          // 16-round tournament merge
            ull h = (ptr < 16) ? heap[lane*16 + ptr] : ~0ull;
            ull m = h;
#pragma unroll
            for (int s = 1; s < 64; s <<= 1) {
                ull o = __shfl_xor(m, s, 64);
                m = (o < m) ? o : m;
            }
            if (h == m && m != ~0ull) ptr++;
            if (lane == r) oi[r] = (int)(m & 0xffffffffu);
        }
        __syncthreads();
    }
}

// ------------------------------------------------- graph conv feature (n,128)
__global__ void k_feature(const float4* __restrict__ vb4, const float4* __restrict__ sup4,
                          const int* __restrict__ idx, float* __restrict__ feat) {
    int b = blockIdx.y, i = blockIdx.x;
    __shared__ float4 dirn[KNN];
    const float4* vb = vb4 + b * N;
    if (threadIdx.x < KNN) {
        int j = idx[(size_t)(b*N + i)*KNN + threadIdx.x];
        float4 q = vb[i], p = vb[j];
        float dx = p.x - q.x, dy = p.y - q.y, dz = p.z - q.z;
        float inv = 1.f / fmaxf(sqrtf(fmaf(dx, dx, fmaf(dy, dy, dz*dz))), 1e-12f);
        dirn[threadIdx.x] = make_float4(dx*inv, dy*inv, dz*inv, 0.f);
    }
    __syncthreads();
    int k = threadIdx.x;
    float acc = 0.f;
#pragma unroll
    for (int s = 0; s < SUP; ++s) {
        float4 sv = sup4[s*KC + k];
        float m = 0.f;                            // relu folded into max
#pragma unroll
        for (int K = 0; K < KNN; ++K) {
            float4 dn = dirn[K];
            float t = fmaf(dn.x, sv.x, fmaf(dn.y, sv.y, dn.z*sv.z));
            m = fmaxf(m, t);
        }
        acc += m;
    }
    feat[(size_t)(b*N + i)*KC + k] = acc * (1.f/SUP);
}

// ------------------------------------------------- neighbor-max + partial mean
__global__ void k_nbmax(const float* __restrict__ feat, const int* __restrict__ idx,
                        float* __restrict__ partial) {
    int b = blockIdx.y;
    int p0 = blockIdx.x * PPB;
    int k = threadIdx.x;
    const float* fb = feat + (size_t)b*N*KC;
    float sum = 0.f;
    for (int p = 0; p < PPB; ++p) {
        const int* ii = idx + (size_t)(b*N + p0 + p) * KNN;
        float m = -3.4e38f;
#pragma unroll
        for (int K = 0; K < KNN; ++K)
            m = fmaxf(m, fb[(size_t)ii[K]*KC + k]);
        sum += m;
    }
    partial[(size_t)(b*(N/PPB) + blockIdx.x)*KC + k] = sum;
}

// ------------------------------------------------- global vec + W2 fold
__global__ void k_global(const float* __restrict__ partial, const float* __restrict__ wconv,
                         float* __restrict__ gconst) {
    int b = blockIdx.x, k = threadIdx.x;
    float s = 0.f;
    for (int q = 0; q < N/PPB; ++q) s += partial[(size_t)(b*(N/PPB) + q)*KC + k];
    __shared__ float fg[KC];
    fg[k] = s * (1.f/N);
    __syncthreads();
    float acc = 0.f;
    for (int c = 0; c < KC; ++c)
        acc = fmaf(fg[c], wconv[k*2*KC + KC + c], acc);
    gconst[b*KC + k] = acc;
}

// ------------------------------------------------- epilogue GEMM + STE + add
__global__ void k_out(const float* __restrict__ feat, const float4* __restrict__ wt4,
                      const float4* __restrict__ wste4, const float4* __restrict__ vb4,
                      const float* __restrict__ gconst, float* __restrict__ out) {
    int p0 = blockIdx.x * OPB;
    int k = threadIdx.x;
    float acc[OPB];
#pragma unroll
    for (int p = 0; p < OPB; ++p) acc[p] = 0.f;
#pragma unroll 4
    for (int c4 = 0; c4 < KC/4; ++c4) {
        float4 w = wt4[c4*KC + k];
#pragma unroll
        for (int p = 0; p < OPB; ++p) {
            const float4 f = *(const float4*)(feat + (size_t)(p0 + p)*KC + c4*4);
            acc[p] = fmaf(f.x, w.x, fmaf(f.y, w.y, fmaf(f.z, w.z, fmaf(f.w, w.w, acc[p]))));
        }
    }
    float4 ws = wste4[k];
#pragma unroll
    for (int p = 0; p < OPB; ++p) {
        int pt = p0 + p;
        int b = pt >> 13;                        // / N
        float4 v = vb4[pt];
        float fste = fmaf(v.x, ws.x, fmaf(v.y, ws.y, v.z*ws.z));
        out[(size_t)pt*KC + k] = acc[p] + gconst[b*KC + k] + feat[(size_t)pt*KC + k] + fste;
    }
}

extern "C" void kernel_launch(void* const* d_in, const int* in_sizes, int n_in,
                              void* d_out, int out_size, void* d_ws, size_t ws_size,
                              hipStream_t stream) {
    const float* verts = (const float*)d_in[0];
    const float* dirs  = (const float*)d_in[1];
    const float* wste  = (const float*)d_in[2];
    const float* wconv = (const float*)d_in[3];
    float* out = (float*)d_out;

    // workspace layout; cand (u16) is dead after select/fallback and aliased as feat
    float* ws = (float*)d_ws;
    float4* vb4   = (float4*)ws;                  // BS*N
    float4* sup4  = vb4 + BS*N;                   // SK
    float4* wste4 = sup4 + SK;                    // KC
    float4* wt4   = wste4 + KC;                   // 32*KC
    float*  thr   = (float*)(wt4 + 32*KC);        // BS*N
    int*    ccnt  = (int*)(thr + BS*N);           // BS*N*NCH
    int*    fbcnt = ccnt + BS*N*NCH;              // 16 (use [0])
    int*    fblist= fbcnt + 16;                   // BS*N
    unsigned short* cand = (unsigned short*)(fblist + BS*N);  // BS*N*CAP u16 (16B aligned)
    float*  feat  = (float*)cand;                 // BS*N*KC floats (8MB <= 12.6MB alias)
    int*    idx   = (int*)(cand + (size_t)BS*N*CAP);     // BS*N*KNN
    float*  partial = (float*)(idx + (size_t)BS*N*KNN);  // BS*(N/PPB)*KC
    float*  gconst  = partial + (size_t)BS*(N/PPB)*KC;   // BS*KC

    hipMemsetAsync(fbcnt, 0, 16*sizeof(int), stream);   // only fbcnt (ccnt fully written)
    k_prep<<<(BS*N + SK + KC + 32*KC + 255)/256, 256, 0, stream>>>(verts, dirs, wste, wconv,
                                                                   vb4, sup4, wste4, wt4);
    k_thr<<<dim3(N/64, BS), 256, 0, stream>>>(vb4, thr);
    k_append<<<dim3(N/QG, NCH, BS), 256, 0, stream>>>(vb4, thr, ccnt, cand);
    k_select<<<dim3(N/64, BS), 64, 0, stream>>>(vb4, ccnt, cand, idx, fbcnt, fblist);
    k_fallback<<<2048, 64, 0, stream>>>(vb4, fbcnt, fblist, idx);
    k_feature<<<dim3(N, BS), KC, 0, stream>>>(vb4, sup4, idx, feat);
    k_nbmax<<<dim3(N/PPB, BS), KC, 0, stream>>>(feat, idx, partial);
    k_global<<<BS, KC, 0, stream>>>(partial, wconv, gconst);
    k_out<<<BS*N/OPB, KC, 0, stream>>>(feat, wt4, wste4, vb4, gconst, out);
}